// Round 7
// baseline (323.984 us; speedup 1.0000x reference)
//
#include <hip/hip_runtime.h>
#include <math.h>

// ---- problem constants ----
#define B   64
#define L   64
#define C   16
#define CHD 64
#define EMB 300
#define D   450       // EMB + 3*50
#define DP  480       // padded bf16 dim count
#define NT  (B*L)     // 4096 tokens per branch
#define NBH 128       // 2 branches * 64 batch

typedef short bf16x8 __attribute__((ext_vector_type(8)));
typedef float f32x4  __attribute__((ext_vector_type(4)));
typedef float f32x2  __attribute__((ext_vector_type(2)));
typedef unsigned short ushort_t;
typedef ushort_t us4 __attribute__((ext_vector_type(4)));

#define MFMA16 __builtin_amdgcn_mfma_f32_16x16x32_bf16

// fragment-major sizes
#define WPF_N (10 * 10 * 512)           // WpadF: 10 nt x 10 ks x 64 lane x 8
#define WBF_N (32 * 15 * 512)           // Wb16F: 32 nt x 15 ks x 64 lane x 8
#define XFRAG 30720                     // per-bh: 4 tiles x 15 ks x 512 (= 64 tok x 480)

#define XFS 456   // f32 row-staging stride (floats)
#define XSS 488   // bf16 row-staging stride

// ---------------- helpers ----------------
__device__ inline float wave_sum(float v) {
#pragma unroll
    for (int o = 32; o; o >>= 1) v += __shfl_xor(v, o, 64);
    return v;
}
__device__ inline ushort_t f2b(float f) {   // RNE float->bf16
    union { float f; unsigned u; } c; c.f = f;
    unsigned r = c.u + 0x7FFFu + ((c.u >> 16) & 1u);
    return (ushort_t)(r >> 16);
}

// ---------------- kernel P: fused weight prep (fragment-major images) ----------------
__global__ __launch_bounds__(256) void prep_kernel(
    const float* __restrict__ W,
    const float* __restrict__ w3, const float* __restrict__ b3,
    const float* __restrict__ w4, const float* __restrict__ b4,
    const float* __restrict__ w5, const float* __restrict__ b5,
    const float* __restrict__ char_emb,
    ushort_t* __restrict__ Wb16F, ushort_t* __restrict__ WpadF,
    float* __restrict__ bias160, ushort_t* __restrict__ ceb16)
{
    int idx = blockIdx.x * 256 + threadIdx.x;
    if (idx < WBF_N) {   // highway weight fragments
        const int e = idx & 7, l = (idx >> 3) & 63, t = idx >> 9;
        const int ks = t % 15, nt = t / 15;
        const int ln = l & 15, q = l >> 4;
        const int n = nt * 16 + ln, k = ks * 32 + q * 8 + e;
        float v = (n < D && k < D) ? W[(size_t)n * D + k] : 0.f;
        Wb16F[idx] = f2b(v);
        return;
    }
    idx -= WBF_N;
    if (idx < WPF_N) {   // conv weight fragments
        const int e = idx & 7, l = (idx >> 3) & 63, t = idx >> 9;
        const int ks = t % 10, nt = t / 10;
        const int ln = l & 15, q = l >> 4;
        const int f = nt * 16 + ln;
        const int kd = ks * 32 + q * 8 + e;
        const int k = kd >> 6, d = kd & 63;
        float v = 0.f;
        if (f < 50)       { if (k < 3) v = w3[f * 192 + d * 3 + k]; }
        else if (f < 100) { if (k < 4) v = w4[(f - 50) * 256 + d * 4 + k]; }
        else if (f < 150) { v = w5[(f - 100) * 320 + d * 5 + k]; }
        WpadF[idx] = f2b(v);
        return;
    }
    idx -= WPF_N;
    if (idx < 160) {
        bias160[idx] = (idx < 50) ? b3[idx] : (idx < 100) ? b4[idx - 50]
                     : (idx < 150) ? b5[idx - 100] : 0.f;
    } else if (idx < 160 + 100 * 64) {
        int i = idx - 160;
        ceb16[i] = f2b(char_emb[i]);
    }
}

// ---------------- kernel 1: fused word-embed copy + char conv -> f32 rows + xbF ----------------
#define ESS 72
#define EST (20 * ESS)

__global__ __launch_bounds__(256) void embed_conv_kernel(
    const int* __restrict__ q1, const int* __restrict__ q2,
    const int* __restrict__ q1c, const int* __restrict__ q2c,
    const float* __restrict__ word_emb, const ushort_t* __restrict__ ceb16,
    const ushort_t* __restrict__ WpadF, const float* __restrict__ bias160,
    float* __restrict__ xout, ushort_t* __restrict__ xbF)
{
    __shared__ ushort_t es[8 * EST];     // 23040 B (f32 smf overlay in epilogue)
    __shared__ ushort_t Xt[8 * XSS];     // 7808 B bf16 row staging

    const int tid  = threadIdx.x;
    const int wv   = tid >> 6;
    const int lane = tid & 63;
    const int ln   = lane & 15, quad = lane >> 4;
    const int bx   = blockIdx.x;
    const int tokbase = ((bx & 7) * 128 + (bx >> 3)) * 8;   // XCD-affine

    // ---- stage char-embedding rows for 8 tokens ----
#pragma unroll
    for (int i = 0; i < 4; ++i) {
        int c = tid + i * 256;
        int row = c >> 3, part = c & 7;
        int tl = row >> 4, cr = row & 15;
        int gtok   = tokbase + tl;
        int branch = gtok >> 12;
        int tokl   = gtok & (NT - 1);
        int cid    = (branch ? q2c : q1c)[tokl * C + cr];
        *(bf16x8*)&es[tl * EST + cr * ESS + part * 8] =
            *(const bf16x8*)&ceb16[cid * 64 + part * 8];
    }
    {   // zero the 4 pad rows per token
        int tl = tid >> 5, rr = (tid >> 3) & 3, part = tid & 7;
        bf16x8 z = {0, 0, 0, 0, 0, 0, 0, 0};
        *(bf16x8*)&es[tl * EST + (16 + rr) * ESS + part * 8] = z;
    }

    // ---- word-embedding copy (f32 global + bf16 LDS staging) ----
#pragma unroll 1
    for (int c = tid; c < 8 * 75; c += 256) {
        const int t  = c / 75, d4 = c - t * 75;
        const int tok    = tokbase + t;
        const int branch = tok >> 12;
        const int tokl   = tok & (NT - 1);
        const int w      = (branch ? q2 : q1)[tokl];
        const float4 v = *(const float4*)(word_emb + (size_t)w * EMB + d4 * 4);
        float* dst = xout + (size_t)tok * D + d4 * 4;
        *(f32x2*)dst       = (f32x2){v.x, v.y};
        *(f32x2*)(dst + 2) = (f32x2){v.z, v.w};
        us4 pk = { f2b(v.x), f2b(v.y), f2b(v.z), f2b(v.w) };
        *(us4*)&Xt[t * XSS + d4 * 4] = pk;
    }
    if (tid < 240) {   // zero bf16 pad cols 450..479
        const int t = tid / 30, k = tid - t * 30;
        Xt[t * XSS + D + k] = 0;
    }
    __syncthreads();

    // ---- conv via MFMA (A from LDS, B coalesced from WpadF) ----
    const int t0 = wv * 2, t1 = t0 + 1;
    f32x4 acc[2][10];
#pragma unroll
    for (int t = 0; t < 2; ++t)
#pragma unroll
        for (int nt = 0; nt < 10; ++nt) acc[t][nt] = (f32x4){0.f, 0.f, 0.f, 0.f};

#pragma unroll 1
    for (int ks = 0; ks < 10; ++ks) {
        const int kk   = ks * 32 + quad * 8;
        const int arow = kk >> 6, aoff = kk & 63;
        bf16x8 a0 = *(const bf16x8*)&es[t0 * EST + (ln + arow) * ESS + aoff];
        bf16x8 a1 = *(const bf16x8*)&es[t1 * EST + (ln + arow) * ESS + aoff];
#pragma unroll
        for (int nt = 0; nt < 10; ++nt) {
            bf16x8 bf = *(const bf16x8*)&WpadF[(size_t)((nt * 10 + ks) << 9) + lane * 8];
            acc[0][nt] = MFMA16(a0, bf, acc[0][nt], 0, 0, 0);
            acc[1][nt] = MFMA16(a1, bf, acc[1][nt], 0, 0, 0);
        }
    }
    __syncthreads();   // es reads done; reuse as f32 staging

    // ---- epilogue: reduce -> LDS, coalesced f32 emit + bf16 staging ----
    float* smf = (float*)es;   // [8][160] f32
#pragma unroll
    for (int t = 0; t < 2; ++t) {
        const int tloc = t0 + t;
#pragma unroll
        for (int nt = 0; nt < 10; ++nt) {
            const int f  = nt * 16 + ln;
            const int Pf = (f < 50) ? 14 : (f < 100) ? 13 : 12;
            float m = -1e30f;
#pragma unroll
            for (int r = 0; r < 4; ++r) {
                const int p = quad * 4 + r;
                if (p < Pf) m = fmaxf(m, acc[t][nt][r]);
            }
            m = fmaxf(m, __shfl_xor(m, 16, 64));
            m = fmaxf(m, __shfl_xor(m, 32, 64));
            if (quad == 0) smf[tloc * 160 + f] = fmaxf(0.f, m + bias160[f]);
        }
    }
    __syncthreads();
#pragma unroll 1
    for (int c = tid; c < 8 * 150; c += 256) {
        const int t = c / 150, f = c - t * 150;
        const float rv = smf[t * 160 + f];
        xout[(size_t)(tokbase + t) * D + EMB + f] = rv;
        Xt[t * XSS + EMB + f] = f2b(rv);
    }
    __syncthreads();

    // ---- fragment-major emit: this block owns half (8 of 16 lanes) of tile tokbase>>4 ----
    {
        const int tile = tokbase >> 4, half = (tokbase >> 3) & 1;
#pragma unroll 1
        for (int c = tid; c < 480; c += 256) {
            const int ksl = c >> 5, s = c & 31;
            const int q = s >> 3, tl = s & 7;
            const int l = q * 16 + half * 8 + tl;
            bf16x8 v = *(const bf16x8*)&Xt[tl * XSS + ksl * 32 + q * 8];
            *(bf16x8*)&xbF[((size_t)(tile * 15 + ksl) * 64 + l) * 8] = v;
        }
    }
}

// ---------------- kernel 2: highway layer 1 (64x64 tiles, fragment-major) ----------------
#define HLS 72

__global__ __launch_bounds__(256, 4) void highway_mfma_kernel(
    const ushort_t* __restrict__ xbFi, const float* __restrict__ xf32,
    const ushort_t* __restrict__ Wb16F, const float* __restrict__ bvec,
    float* __restrict__ out, ushort_t* __restrict__ xbFo)
{
    __shared__ ushort_t Xl[64 * HLS];   // 9216 B

    const int bx = blockIdx.x;
    const int cx = bx & 7, rr = bx >> 3;        // cx = XCD
    const int my = cx * 16 + (rr & 15);         // token panel (64 tokens)
    const int mx = rr >> 4;                     // n panel (64 dims)

    const int tid  = threadIdx.x;
    const int wv   = tid >> 6;
    const int lane = tid & 63;
    const int wm = wv >> 1, wn = wv & 1;
    const int m0 = my * 64 + wm * 32;
    const int n0 = mx * 64 + wn * 32;
    const int lm = lane & 15, quad = lane >> 4;

    const int tA0 = my * 4 + wm * 2;
    const ushort_t* ax0 = xbFi + (size_t)(tA0 * 15) * 512 + lane * 8;
    const ushort_t* ax1 = ax0 + 15 * 512;
    const int ntg0 = mx * 4 + wn * 2;
    const ushort_t* bw0 = Wb16F + (size_t)(ntg0 * 15) * 512 + lane * 8;
    const ushort_t* bw1 = bw0 + 15 * 512;

    f32x4 acc[2][2];
#pragma unroll
    for (int i = 0; i < 2; ++i)
#pragma unroll
        for (int j = 0; j < 2; ++j) acc[i][j] = (f32x4){0.f, 0.f, 0.f, 0.f};

#pragma unroll 3
    for (int ks = 0; ks < 15; ++ks) {
        bf16x8 a0 = *(const bf16x8*)(ax0 + ks * 512);
        bf16x8 a1 = *(const bf16x8*)(ax1 + ks * 512);
        bf16x8 b0 = *(const bf16x8*)(bw0 + ks * 512);
        bf16x8 b1 = *(const bf16x8*)(bw1 + ks * 512);
        acc[0][0] = MFMA16(a0, b0, acc[0][0], 0, 0, 0);
        acc[0][1] = MFMA16(a0, b1, acc[0][1], 0, 0, 0);
        acc[1][0] = MFMA16(a1, b0, acc[1][0], 0, 0, 0);
        acc[1][1] = MFMA16(a1, b1, acc[1][1], 0, 0, 0);
    }

#pragma unroll
    for (int nt = 0; nt < 2; ++nt) {
        const int n  = n0 + nt * 16 + lm;
        const int nl = wn * 32 + nt * 16 + lm;
        const bool nval = (n < D);
        const float bv = nval ? bvec[n] : 0.f;
#pragma unroll
        for (int mt = 0; mt < 2; ++mt) {
#pragma unroll
            for (int r = 0; r < 4; ++r) {
                const int m  = m0 + mt * 16 + quad * 4 + r;
                const int ml = wm * 32 + mt * 16 + quad * 4 + r;
                float y = acc[mt][nt][r] + bv;
                float g = 1.f / (1.f + __expf(-y));
                float o = 0.f;
                if (nval) {
                    float xo = xf32[(size_t)m * D + n];
                    o = g * fmaxf(y, 0.f) + (1.f - g) * xo;
                    out[(size_t)m * D + n] = o;
                }
                Xl[ml * HLS + nl] = f2b(nval ? o : 0.f);
            }
        }
    }
    __syncthreads();

    // ---- fragment-major emit: 4 token tiles x 2 ks slots ----
#pragma unroll 1
    for (int c = tid; c < 512; c += 256) {
        const int fi = c >> 6, l = c & 63;
        const int tl = fi >> 1, ksl = fi & 1;
        const int ksg = mx * 2 + ksl;
        if (ksg < 15) {
            const int lnp = l & 15, qp = l >> 4;
            bf16x8 v = *(const bf16x8*)&Xl[(tl * 16 + lnp) * HLS + ksl * 32 + qp * 8];
            *(bf16x8*)&xbFo[((size_t)((my * 4 + tl) * 15 + ksg) * 64 + l) * 8] = v;
        }
    }
}

// ---------------- kernel 3: highway layer 2 + attn-prep layer 0 ----------------
// one block per 16-token tile (grid 512, XCD-affine); full 480-n rows per block.
__global__ __launch_bounds__(256) void highway2_prep_kernel(
    const ushort_t* __restrict__ xbFi, const float* __restrict__ xf32in,
    const ushort_t* __restrict__ Wb16F, const float* __restrict__ bvec,
    const float* __restrict__ attn_w,                      // layer-0 w1|w2|w3
    float* __restrict__ outf, ushort_t* __restrict__ xbFo,
    ushort_t* __restrict__ xw3F, ushort_t* __restrict__ xTF,
    float* __restrict__ s1g, float* __restrict__ s2g)
{
    __shared__ float    Xf[16 * XFS];   // 29184 B
    __shared__ ushort_t Xs[16 * XSS];   // 15616 B

    const int bx  = blockIdx.x;
    const int wid = (bx & 7) * 64 + (bx >> 3);
    const int bh  = wid >> 2, jq = wid & 3;
    const int tt  = wid;                 // global 16-token tile
    const int m0  = tt * 16;
    const int tid = threadIdx.x;
    const int wv  = tid >> 6;
    const int lane = tid & 63;
    const int ln = lane & 15, quad = lane >> 4;

    if (tid < 480) {   // zero bf16 pad cols 450..479
        const int t = tid / 30, k = tid - t * 30;
        Xs[t * XSS + D + k] = 0;
    }

    // ---- MFMA: wave wv owns n-tiles wv*8 .. wv*8+7 (clipped to <30) ----
    const ushort_t* ax = xbFi + (size_t)(tt * 15) * 512 + lane * 8;
    f32x4 acc[8];
#pragma unroll
    for (int t = 0; t < 8; ++t) acc[t] = (f32x4){0.f, 0.f, 0.f, 0.f};

#pragma unroll 1
    for (int ks = 0; ks < 15; ++ks) {
        bf16x8 a = *(const bf16x8*)(ax + ks * 512);
#pragma unroll
        for (int t = 0; t < 8; ++t) {
            const int nt = wv * 8 + t;
            if (nt < 30) {
                bf16x8 b = *(const bf16x8*)&Wb16F[(size_t)(nt * 15 + ks) * 512 + lane * 8];
                acc[t] = MFMA16(a, b, acc[t], 0, 0, 0);
            }
        }
    }

    // ---- highway epilogue: f32 out + LDS staging ----
#pragma unroll
    for (int t = 0; t < 8; ++t) {
        const int nt = wv * 8 + t;
        if (nt >= 30) continue;
        const int n = nt * 16 + ln;
        const bool nval = (n < D);
        const float bv = nval ? bvec[n] : 0.f;
#pragma unroll
        for (int reg = 0; reg < 4; ++reg) {
            const int i = quad * 4 + reg;   // local row
            float y = acc[t][reg] + bv;
            float g = 1.f / (1.f + __expf(-y));
            if (nval) {
                float xo = xf32in[(size_t)(m0 + i) * D + n];
                float o = g * fmaxf(y, 0.f) + (1.f - g) * xo;
                outf[(size_t)(m0 + i) * D + n] = o;
                Xf[i * XFS + n] = o;
                Xs[i * XSS + n] = f2b(o);
            }
        }
    }
    __syncthreads();

    // ---- attn-prep (layer 0) from LDS ----
    const float* wb = attn_w;           // w1 | w2 | w3
    const float* w3 = wb + 2 * D;

    // s1/s2 dots: 4 rows per wave (order matches old prep exactly)
#pragma unroll 1
    for (int rr = 0; rr < 4; ++rr) {
        const int j = wv * 4 + rr;
        float a1 = 0.f, a2 = 0.f;
#pragma unroll
        for (int t = 0; t < 8; ++t) {
            const int k = lane + t * 64;
            if (k < D) {
                float xv = Xf[j * XFS + k];
                a1 = fmaf(xv, wb[k], a1);
                a2 = fmaf(xv, wb[D + k], a2);
            }
        }
        a1 = wave_sum(a1);
        a2 = wave_sum(a2);
        if (lane == 0) { s1g[m0 + j] = a1; s2g[m0 + j] = a2; }
    }

    // xbF + xw3F fragment emit
#pragma unroll 1
    for (int c = tid; c < 960; c += 256) {
        const int ks = c >> 6, l = c & 63;
        const int lnp = l & 15, qp = l >> 4;
        bf16x8 v = *(const bf16x8*)&Xs[lnp * XSS + ks * 32 + qp * 8];
        *(bf16x8*)&xbFo[((size_t)(tt * 15 + ks) * 64 + l) * 8] = v;
        bf16x8 pv;
#pragma unroll
        for (int e = 0; e < 8; ++e) {
            const int k = ks * 32 + qp * 8 + e;
            const float x = (k < D) ? Xf[lnp * XFS + k] : 0.f;
            pv[e] = (short)f2b((k < D) ? x * w3[k] : 0.f);
        }
        *(bf16x8*)&xw3F[(size_t)bh * XFRAG + ((jq * 15 + ks) * 64 + l) * 8] = pv;
    }

    // xTF emit (transpose; same quad-pattern as old prep)
    {
        const int half = jq >> 1, q0 = (jq & 1) * 2;
#pragma unroll 1
        for (int c = tid; c < 960; c += 256) {
            const int dt = c >> 5, s = c & 31;
            const int qp = q0 + (s >> 4), lnp = s & 15;
            const int d  = dt * 16 + lnp;
            const int jb = (qp & 1) * 8;
            bf16x8 v;
#pragma unroll
            for (int e = 0; e < 8; ++e) v[e] = (short)Xs[(jb + e) * XSS + d];
            *(bf16x8*)&xTF[(size_t)bh * XFRAG + ((dt * 2 + half) * 64 + qp * 16 + lnp) * 8] = v;
        }
    }
}

// ---------------- kernel 4: attn core layer 0 + attn-prep layer 1 ----------------
#define ALS 72

__global__ __launch_bounds__(256) void attn_core_prep_kernel(
    const float* __restrict__ xf32,          // residual (buf0)
    const ushort_t* __restrict__ xF, const ushort_t* __restrict__ xw3F,
    const ushort_t* __restrict__ xTF,
    const float* __restrict__ s1g, const float* __restrict__ s2g,
    const int* __restrict__ q1_len, const int* __restrict__ q2_len,
    const float* __restrict__ attn_b, const float* __restrict__ attn_w,
    ushort_t* __restrict__ xbFo,
    ushort_t* __restrict__ xw3Fo, ushort_t* __restrict__ xTFo,
    float* __restrict__ s1o, float* __restrict__ s2o)
{
    __shared__ float    sc[16][68];    // 4352 B
    __shared__ ushort_t Al[16 * ALS];  // 2304 B
    __shared__ float    Af[16 * XFS];  // 29184 B
    __shared__ ushort_t At[16 * XSS];  // 15616 B

    const int bx  = blockIdx.x;
    const int wid = (bx & 7) * 64 + (bx >> 3);
    const int bh  = wid >> 2, iq = wid & 3;
    const int branch = bh >> 6, b = bh & 63;
    const int tid  = threadIdx.x;
    const int wv   = tid >> 6;
    const int lane = tid & 63;
    const int ln   = lane & 15, quad = lane >> 4;
    const int i0   = iq * 16;
    const int m0   = bh * 64 + i0;

    if (tid < 480) {   // zero bf16 pad cols
        const int t = tid / 30, k = tid - t * 30;
        At[t * XSS + D + k] = 0;
    }

    // ---- QK^T (layer 0) ----
    const ushort_t* xa = xF   + (size_t)bh * XFRAG + (iq * 15 * 64 + lane) * 8;
    const ushort_t* xb = xw3F + (size_t)bh * XFRAG + (wv * 15 * 64 + lane) * 8;

    f32x4 qa0 = (f32x4){0.f, 0.f, 0.f, 0.f};
    f32x4 qa1 = (f32x4){0.f, 0.f, 0.f, 0.f};
#pragma unroll
    for (int ks = 0; ks < 14; ks += 2) {
        bf16x8 a0 = *(const bf16x8*)(xa + ks * 512);
        bf16x8 b0 = *(const bf16x8*)(xb + ks * 512);
        bf16x8 a1 = *(const bf16x8*)(xa + ks * 512 + 512);
        bf16x8 b1 = *(const bf16x8*)(xb + ks * 512 + 512);
        qa0 = MFMA16(a0, b0, qa0, 0, 0, 0);
        qa1 = MFMA16(a1, b1, qa1, 0, 0, 0);
    }
    {
        bf16x8 a  = *(const bf16x8*)(xa + 14 * 512);
        bf16x8 bq = *(const bf16x8*)(xb + 14 * 512);
        qa0 = MFMA16(a, bq, qa0, 0, 0, 0);
    }
    f32x4 qacc = qa0 + qa1;

    const int   len  = (branch ? q2_len : q1_len)[b];
    const float bias = attn_b[0];
    const int   j    = wv * 16 + ln;
    const float s2v  = s2g[bh * 64 + j];
#pragma unroll
    for (int reg = 0; reg < 4; ++reg) {
        const int i = i0 + quad * 4 + reg;
        float v = qacc[reg] + s1g[bh * 64 + i] + s2v + bias;
        if (j >= len) v = -1e-9f;        // reference's (buggy) mask value
        sc[quad * 4 + reg][j] = v;
    }
    __syncthreads();

    // ---- softmax ----
#pragma unroll
    for (int rr = 0; rr < 4; ++rr) {
        const int r = wv * 4 + rr;
        float v = sc[r][lane];
        float m = v;
#pragma unroll
        for (int o = 32; o; o >>= 1) m = fmaxf(m, __shfl_xor(m, o, 64));
        float ev = __expf(v - m);
        float sm = ev;
#pragma unroll
        for (int o = 32; o; o >>= 1) sm += __shfl_xor(sm, o, 64);
        Al[r * ALS + lane] = f2b(ev * (1.f / sm));
    }
    __syncthreads();

    // ---- AV + residual -> LDS staging only (no f32 global write) ----
    const ushort_t* xTb = xTF + (size_t)bh * XFRAG + lane * 8;
    bf16x8 af0 = *(const bf16x8*)&Al[ln * ALS + quad * 8];
    bf16x8 af1 = *(const bf16x8*)&Al[ln * ALS + quad * 8 + 32];

#pragma unroll 2
    for (int dt = wv; dt < 30; dt += 4) {
        bf16x8 b0 = *(const bf16x8*)(xTb + dt * 1024);
        bf16x8 b1 = *(const bf16x8*)(xTb + dt * 1024 + 512);
        f32x4 acc = (f32x4){0.f, 0.f, 0.f, 0.f};
        acc = MFMA16(af0, b0, acc, 0, 0, 0);
        acc = MFMA16(af1, b1, acc, 0, 0, 0);

        const int d = dt * 16 + ln;
        if (d < D) {
#pragma unroll
            for (int reg = 0; reg < 4; ++reg) {
                const int il = quad * 4 + reg;
                float v = acc[reg] + xf32[(size_t)(m0 + il) * D + d];
                Af[il * XFS + d] = v;
                At[il * XSS + d] = f2b(v);
            }
        }
    }
    __syncthreads();

    // ---- attn-prep (layer 1) from LDS ----
    const float* wb1 = attn_w + 3 * D;   // layer-1 w1 | w2 | w3
    const float* w31 = wb1 + 2 * D;

#pragma unroll 1
    for (int rr = 0; rr < 4; ++rr) {
        const int jj = wv * 4 + rr;
        float a1 = 0.f, a2 = 0.f;
#pragma unroll
        for (int t = 0; t < 8; ++t) {
            const int k = lane + t * 64;
            if (k < D) {
                float xv = Af[jj * XFS + k];
                a1 = fmaf(xv, wb1[k], a1);
                a2 = fmaf(xv, wb1[D + k], a2);
            }
        }
        a1 = wave_sum(a1);
        a2 = wave_sum(a2);
        if (lane == 0) { s1o[m0 + jj] = a1; s2o[m0 + jj] = a2; }
    }

#pragma unroll 1
    for (int c = tid; c < 960; c += 256) {
        const int ks = c >> 6, l = c & 63;
        const int lnp = l & 15, qp = l >> 4;
        bf16x8 v = *(const bf16x8*)&At[lnp * XSS + ks * 32 + qp * 8];
        *(bf16x8*)&xbFo[((size_t)((bh * 4 + iq) * 15 + ks) * 64 + l) * 8] = v;
        bf16x8 pv;
#pragma unroll
        for (int e = 0; e < 8; ++e) {
            const int k = ks * 32 + qp * 8 + e;
            const float x = (k < D) ? Af[lnp * XFS + k] : 0.f;
            pv[e] = (short)f2b((k < D) ? x * w31[k] : 0.f);
        }
        *(bf16x8*)&xw3Fo[(size_t)bh * XFRAG + ((iq * 15 + ks) * 64 + l) * 8] = pv;
    }

    {
        const int half = iq >> 1, q0 = (iq & 1) * 2;
#pragma unroll 1
        for (int c = tid; c < 960; c += 256) {
            const int dt = c >> 5, s = c & 31;
            const int qp = q0 + (s >> 4), lnp = s & 15;
            const int d  = dt * 16 + lnp;
            const int jb = (qp & 1) * 8;
            bf16x8 v;
#pragma unroll
            for (int e = 0; e < 8; ++e) v[e] = (short)At[(jb + e) * XSS + d];
            *(bf16x8*)&xTFo[(size_t)bh * XFRAG + ((dt * 2 + half) * 64 + qp * 16 + lnp) * 8] = v;
        }
    }
}

// ---------------- kernel 5: attn core layer 1 -> final output ----------------
__global__ __launch_bounds__(256) void attn_core_final_kernel(
    const ushort_t* __restrict__ xF, const ushort_t* __restrict__ xw3F,
    const ushort_t* __restrict__ xTF,
    const float* __restrict__ s1g, const float* __restrict__ s2g,
    const int* __restrict__ q1_len, const int* __restrict__ q2_len,
    const float* __restrict__ attn_b,
    float* __restrict__ outf)
{
    __shared__ float    sc[16][68];
    __shared__ ushort_t Al[16 * ALS];

    const int bx  = blockIdx.x;
    const int wid = (bx & 7) * 64 + (bx >> 3);
    const int bh  = wid >> 2, iq = wid & 3;
    const int branch = bh >> 6, b = bh & 63;
    const int tid  = threadIdx.x;
    const int wv   = tid >> 6;
    const int lane = tid & 63;
    const int ln   = lane & 15, quad = lane >> 4;
    const int i0   = iq * 16;

    const ushort_t* xa = xF   + (size_t)bh * XFRAG + (iq * 15 * 64 + lane) * 8;
    const ushort_t* xb = xw3F + (size_t)bh * XFRAG + (wv * 15 * 64 + lane) * 8;

    f32x4 qa0 = (f32x4){0.f, 0.f, 0.f, 0.f};
    f32x4 qa1 = (f32x4){0.f, 0.f, 0.f, 0.f};
#pragma unroll
    for (int ks = 0; ks < 14; ks += 2) {
        bf16x8 a0 = *(const bf16x8*)(xa + ks * 512);
        bf16x8 b0 = *(const bf16x8*)(xb + ks * 512);
        bf16x8 a1 = *(const bf16x8*)(xa + ks * 512 + 512);
        bf16x8 b1 = *(const bf16x8*)(xb + ks * 512 + 512);
        qa0 = MFMA16(a0, b0, qa0, 0, 0, 0);
        qa1 = MFMA16(a1, b1, qa1, 0, 0, 0);
    }
    {
        bf16x8 a  = *(const bf16x8*)(xa + 14 * 512);
        bf16x8 bq = *(const bf16x8*)(xb + 14 * 512);
        qa0 = MFMA16(a, bq, qa0, 0, 0, 0);
    }
    f32x4 qacc = qa0 + qa1;

    const int   len  = (branch ? q2_len : q1_len)[b];
    const float bias = attn_b[1];
    const int   j    = wv * 16 + ln;
    const float s2v  = s2g[bh * 64 + j];
#pragma unroll
    for (int reg = 0; reg < 4; ++reg) {
        const int i = i0 + quad * 4 + reg;
        float v = qacc[reg] + s1g[bh * 64 + i] + s2v + bias;
        if (j >= len) v = -1e-9f;
        sc[quad * 4 + reg][j] = v;
    }
    __syncthreads();

#pragma unroll
    for (int rr = 0; rr < 4; ++rr) {
        const int r = wv * 4 + rr;
        float v = sc[r][lane];
        float m = v;
#pragma unroll
        for (int o = 32; o; o >>= 1) m = fmaxf(m, __shfl_xor(m, o, 64));
        float ev = __expf(v - m);
        float sm = ev;
#pragma unroll
        for (int o = 32; o; o >>= 1) sm += __shfl_xor(sm, o, 64);
        Al[r * ALS + lane] = f2b(ev * (1.f / sm));
    }
    __syncthreads();

    const ushort_t* xTb = xTF + (size_t)bh * XFRAG + lane * 8;
    bf16x8 af0 = *(const bf16x8*)&Al[ln * ALS + quad * 8];
    bf16x8 af1 = *(const bf16x8*)&Al[ln * ALS + quad * 8 + 32];

#pragma unroll 2
    for (int dt = wv; dt < 30; dt += 4) {
        bf16x8 b0 = *(const bf16x8*)(xTb + dt * 1024);
        bf16x8 b1 = *(const bf16x8*)(xTb + dt * 1024 + 512);
        f32x4 acc = (f32x4){0.f, 0.f, 0.f, 0.f};
        acc = MFMA16(af0, b0, acc, 0, 0, 0);
        acc = MFMA16(af1, b1, acc, 0, 0, 0);

        const int d = dt * 16 + ln;
        if (d < D) {
#pragma unroll
            for (int reg = 0; reg < 4; ++reg) {
                const int i = i0 + quad * 4 + reg;
                outf[((size_t)bh * 64 + i) * D + d] = acc[reg];
            }
        }
    }
}

// ---------------- launch ----------------
extern "C" void kernel_launch(void* const* d_in, const int* in_sizes, int n_in,
                              void* d_out, int out_size, void* d_ws, size_t ws_size,
                              hipStream_t stream) {
    const int*   q1       = (const int*)  d_in[0];
    const int*   q2       = (const int*)  d_in[1];
    const int*   q1_len   = (const int*)  d_in[2];
    const int*   q2_len   = (const int*)  d_in[3];
    const int*   q1c      = (const int*)  d_in[4];
    const int*   q2c      = (const int*)  d_in[5];
    const float* word_emb = (const float*)d_in[6];
    const float* char_emb = (const float*)d_in[7];
    const float* w3       = (const float*)d_in[8];
    const float* b3       = (const float*)d_in[9];
    const float* w4       = (const float*)d_in[10];
    const float* b4       = (const float*)d_in[11];
    const float* w5       = (const float*)d_in[12];
    const float* b5       = (const float*)d_in[13];
    const float* hw_w     = (const float*)d_in[14];
    const float* hw_b     = (const float*)d_in[15];
    const float* attn_w   = (const float*)d_in[16];
    const float* attn_b   = (const float*)d_in[17];
    float* out = (float*)d_out;

    float*    buf0    = (float*)d_ws;                          // 2*NT*D f32
    float*    buf1    = buf0 + (size_t)2 * NT * D;             // 2*NT*D f32
    float*    bias160 = buf1 + (size_t)2 * NT * D;             // 160 f32
    ushort_t* xbFa    = (ushort_t*)(bias160 + 160);            // 2*NT*DP bf16 (fragment-major)
    ushort_t* xbFb    = xbFa + (size_t)2 * NT * DP;            // 2*NT*DP bf16
    ushort_t* Wb16F   = xbFb + (size_t)2 * NT * DP;            // WBF_N bf16
    ushort_t* WpadF   = Wb16F + (size_t)WBF_N;                 // WPF_N bf16
    ushort_t* ceb16   = WpadF + (size_t)WPF_N;                 // 100*64 bf16
    ushort_t* xw3Fa   = ceb16 + (size_t)100 * 64;              // NBH*XFRAG bf16
    ushort_t* xTFa    = xw3Fa + (size_t)NBH * XFRAG;           // NBH*XFRAG bf16
    ushort_t* xw3Fb   = xTFa  + (size_t)NBH * XFRAG;           // NBH*XFRAG bf16
    ushort_t* xTFb    = xw3Fb + (size_t)NBH * XFRAG;           // NBH*XFRAG bf16
    float*    s1a     = (float*)(xTFb + (size_t)NBH * XFRAG);  // 2*NT f32
    float*    s2a     = s1a + (size_t)2 * NT;
    float*    s1b     = s2a + (size_t)2 * NT;
    float*    s2b     = s1b + (size_t)2 * NT;

    // 1. weight prep + fused embed/conv -> buf0 + xbFa
    prep_kernel<<<(WBF_N + WPF_N + 160 + 100 * 64 + 255) / 256, 256, 0, stream>>>(
        hw_w, w3, b3, w4, b4, w5, b5, char_emb, Wb16F, WpadF, bias160, ceb16);
    embed_conv_kernel<<<1024, 256, 0, stream>>>(q1, q2, q1c, q2c, word_emb, ceb16,
                                                WpadF, bias160, buf0, xbFa);

    // 2. highway layer 1 (64x64 tiles)
    highway_mfma_kernel<<<1024, 256, 0, stream>>>(xbFa, buf0, Wb16F, hw_b, buf1, xbFb);

    // 3. highway layer 2 + attn-prep layer 0 (full-row blocks)
    highway2_prep_kernel<<<512, 256, 0, stream>>>(
        xbFb, buf1, Wb16F, hw_b, attn_w, buf0, xbFa, xw3Fa, xTFa, s1a, s2a);

    // 4. attn core layer 0 + attn-prep layer 1
    attn_core_prep_kernel<<<512, 256, 0, stream>>>(
        buf0, xbFa, xw3Fa, xTFa, s1a, s2a, q1_len, q2_len, attn_b, attn_w,
        xbFb, xw3Fb, xTFb, s1b, s2b);

    // 5. attn core layer 1 -> out
    attn_core_final_kernel<<<512, 256, 0, stream>>>(
        xbFb, xw3Fb, xTFb, s1b, s2b, q1_len, q2_len, attn_b, out);
}

// Round 8
// 305.954 us; speedup vs baseline: 1.0589x; 1.0589x over previous
//
#include <hip/hip_runtime.h>
#include <math.h>

// ---- problem constants ----
#define B   64
#define L   64
#define C   16
#define CHD 64
#define EMB 300
#define D   450       // EMB + 3*50
#define DP  480       // padded bf16 dim count
#define NT  (B*L)     // 4096 tokens per branch
#define NBH 128       // 2 branches * 64 batch

typedef short bf16x8 __attribute__((ext_vector_type(8)));
typedef float f32x4  __attribute__((ext_vector_type(4)));
typedef float f32x2  __attribute__((ext_vector_type(2)));
typedef unsigned short ushort_t;
typedef ushort_t us4 __attribute__((ext_vector_type(4)));

#define MFMA16 __builtin_amdgcn_mfma_f32_16x16x32_bf16

// fragment-major sizes
#define WPF_N (10 * 10 * 512)           // WpadF: 10 nt x 10 ks x 64 lane x 8
#define WBF_N (32 * 15 * 512)           // Wb16F: 32 nt x 15 ks x 64 lane x 8
#define XFRAG 30720                     // per-bh: 4 tiles x 15 ks x 512 (= 64 tok x 480)

#define XFS 456   // f32 row-staging stride (floats)
#define XSS 488   // bf16 row-staging stride (embed_conv only)

// ---------------- helpers ----------------
__device__ inline float wave_sum(float v) {
#pragma unroll
    for (int o = 32; o; o >>= 1) v += __shfl_xor(v, o, 64);
    return v;
}
__device__ inline ushort_t f2b(float f) {   // RNE float->bf16
    union { float f; unsigned u; } c; c.f = f;
    unsigned r = c.u + 0x7FFFu + ((c.u >> 16) & 1u);
    return (ushort_t)(r >> 16);
}

// ---------------- kernel P: fused weight prep (fragment-major images) ----------------
__global__ __launch_bounds__(256) void prep_kernel(
    const float* __restrict__ W,
    const float* __restrict__ w3, const float* __restrict__ b3,
    const float* __restrict__ w4, const float* __restrict__ b4,
    const float* __restrict__ w5, const float* __restrict__ b5,
    const float* __restrict__ char_emb,
    ushort_t* __restrict__ Wb16F, ushort_t* __restrict__ WpadF,
    float* __restrict__ bias160, ushort_t* __restrict__ ceb16)
{
    int idx = blockIdx.x * 256 + threadIdx.x;
    if (idx < WBF_N) {   // highway weight fragments
        const int e = idx & 7, l = (idx >> 3) & 63, t = idx >> 9;
        const int ks = t % 15, nt = t / 15;
        const int ln = l & 15, q = l >> 4;
        const int n = nt * 16 + ln, k = ks * 32 + q * 8 + e;
        float v = (n < D && k < D) ? W[(size_t)n * D + k] : 0.f;
        Wb16F[idx] = f2b(v);
        return;
    }
    idx -= WBF_N;
    if (idx < WPF_N) {   // conv weight fragments
        const int e = idx & 7, l = (idx >> 3) & 63, t = idx >> 9;
        const int ks = t % 10, nt = t / 10;
        const int ln = l & 15, q = l >> 4;
        const int f = nt * 16 + ln;
        const int kd = ks * 32 + q * 8 + e;
        const int k = kd >> 6, d = kd & 63;
        float v = 0.f;
        if (f < 50)       { if (k < 3) v = w3[f * 192 + d * 3 + k]; }
        else if (f < 100) { if (k < 4) v = w4[(f - 50) * 256 + d * 4 + k]; }
        else if (f < 150) { v = w5[(f - 100) * 320 + d * 5 + k]; }
        WpadF[idx] = f2b(v);
        return;
    }
    idx -= WPF_N;
    if (idx < 160) {
        bias160[idx] = (idx < 50) ? b3[idx] : (idx < 100) ? b4[idx - 50]
                     : (idx < 150) ? b5[idx - 100] : 0.f;
    } else if (idx < 160 + 100 * 64) {
        int i = idx - 160;
        ceb16[i] = f2b(char_emb[i]);
    }
}

// ---------------- kernel 1: fused word-embed copy + char conv -> f32 rows + xbF ----------------
#define ESS 72
#define EST (20 * ESS)

__global__ __launch_bounds__(256) void embed_conv_kernel(
    const int* __restrict__ q1, const int* __restrict__ q2,
    const int* __restrict__ q1c, const int* __restrict__ q2c,
    const float* __restrict__ word_emb, const ushort_t* __restrict__ ceb16,
    const ushort_t* __restrict__ WpadF, const float* __restrict__ bias160,
    float* __restrict__ xout, ushort_t* __restrict__ xbF)
{
    __shared__ ushort_t es[8 * EST];     // 23040 B (f32 smf overlay in epilogue)
    __shared__ ushort_t Xt[8 * XSS];     // 7808 B bf16 row staging

    const int tid  = threadIdx.x;
    const int wv   = tid >> 6;
    const int lane = tid & 63;
    const int ln   = lane & 15, quad = lane >> 4;
    const int bx   = blockIdx.x;
    const int tokbase = ((bx & 7) * 128 + (bx >> 3)) * 8;   // XCD-affine

    // ---- stage char-embedding rows for 8 tokens ----
#pragma unroll
    for (int i = 0; i < 4; ++i) {
        int c = tid + i * 256;
        int row = c >> 3, part = c & 7;
        int tl = row >> 4, cr = row & 15;
        int gtok   = tokbase + tl;
        int branch = gtok >> 12;
        int tokl   = gtok & (NT - 1);
        int cid    = (branch ? q2c : q1c)[tokl * C + cr];
        *(bf16x8*)&es[tl * EST + cr * ESS + part * 8] =
            *(const bf16x8*)&ceb16[cid * 64 + part * 8];
    }
    {   // zero the 4 pad rows per token
        int tl = tid >> 5, rr = (tid >> 3) & 3, part = tid & 7;
        bf16x8 z = {0, 0, 0, 0, 0, 0, 0, 0};
        *(bf16x8*)&es[tl * EST + (16 + rr) * ESS + part * 8] = z;
    }

    // ---- word-embedding copy (f32 global + bf16 LDS staging) ----
#pragma unroll 1
    for (int c = tid; c < 8 * 75; c += 256) {
        const int t  = c / 75, d4 = c - t * 75;
        const int tok    = tokbase + t;
        const int branch = tok >> 12;
        const int tokl   = tok & (NT - 1);
        const int w      = (branch ? q2 : q1)[tokl];
        const float4 v = *(const float4*)(word_emb + (size_t)w * EMB + d4 * 4);
        float* dst = xout + (size_t)tok * D + d4 * 4;
        *(f32x2*)dst       = (f32x2){v.x, v.y};
        *(f32x2*)(dst + 2) = (f32x2){v.z, v.w};
        us4 pk = { f2b(v.x), f2b(v.y), f2b(v.z), f2b(v.w) };
        *(us4*)&Xt[t * XSS + d4 * 4] = pk;
    }
    if (tid < 240) {   // zero bf16 pad cols 450..479
        const int t = tid / 30, k = tid - t * 30;
        Xt[t * XSS + D + k] = 0;
    }
    __syncthreads();

    // ---- conv via MFMA (A from LDS, B coalesced from WpadF) ----
    const int t0 = wv * 2, t1 = t0 + 1;
    f32x4 acc[2][10];
#pragma unroll
    for (int t = 0; t < 2; ++t)
#pragma unroll
        for (int nt = 0; nt < 10; ++nt) acc[t][nt] = (f32x4){0.f, 0.f, 0.f, 0.f};

#pragma unroll 1
    for (int ks = 0; ks < 10; ++ks) {
        const int kk   = ks * 32 + quad * 8;
        const int arow = kk >> 6, aoff = kk & 63;
        bf16x8 a0 = *(const bf16x8*)&es[t0 * EST + (ln + arow) * ESS + aoff];
        bf16x8 a1 = *(const bf16x8*)&es[t1 * EST + (ln + arow) * ESS + aoff];
#pragma unroll
        for (int nt = 0; nt < 10; ++nt) {
            bf16x8 bf = *(const bf16x8*)&WpadF[(size_t)((nt * 10 + ks) << 9) + lane * 8];
            acc[0][nt] = MFMA16(a0, bf, acc[0][nt], 0, 0, 0);
            acc[1][nt] = MFMA16(a1, bf, acc[1][nt], 0, 0, 0);
        }
    }
    __syncthreads();   // es reads done; reuse as f32 staging

    // ---- epilogue: reduce -> LDS, coalesced f32 emit + bf16 staging ----
    float* smf = (float*)es;   // [8][160] f32
#pragma unroll
    for (int t = 0; t < 2; ++t) {
        const int tloc = t0 + t;
#pragma unroll
        for (int nt = 0; nt < 10; ++nt) {
            const int f  = nt * 16 + ln;
            const int Pf = (f < 50) ? 14 : (f < 100) ? 13 : 12;
            float m = -1e30f;
#pragma unroll
            for (int r = 0; r < 4; ++r) {
                const int p = quad * 4 + r;
                if (p < Pf) m = fmaxf(m, acc[t][nt][r]);
            }
            m = fmaxf(m, __shfl_xor(m, 16, 64));
            m = fmaxf(m, __shfl_xor(m, 32, 64));
            if (quad == 0) smf[tloc * 160 + f] = fmaxf(0.f, m + bias160[f]);
        }
    }
    __syncthreads();
#pragma unroll 1
    for (int c = tid; c < 8 * 150; c += 256) {
        const int t = c / 150, f = c - t * 150;
        const float rv = smf[t * 160 + f];
        xout[(size_t)(tokbase + t) * D + EMB + f] = rv;
        Xt[t * XSS + EMB + f] = f2b(rv);
    }
    __syncthreads();

    // ---- fragment-major emit: this block owns half (8 of 16 lanes) of tile tokbase>>4 ----
    {
        const int tile = tokbase >> 4, half = (tokbase >> 3) & 1;
#pragma unroll 1
        for (int c = tid; c < 480; c += 256) {
            const int ksl = c >> 5, s = c & 31;
            const int q = s >> 3, tl = s & 7;
            const int l = q * 16 + half * 8 + tl;
            bf16x8 v = *(const bf16x8*)&Xt[tl * XSS + ksl * 32 + q * 8];
            *(bf16x8*)&xbF[((size_t)(tile * 15 + ksl) * 64 + l) * 8] = v;
        }
    }
}

// ---------------- kernel 2: highway layer 1 (64x64 tiles, fragment-major) ----------------
#define HLS 72

__global__ __launch_bounds__(256, 4) void highway_mfma_kernel(
    const ushort_t* __restrict__ xbFi, const float* __restrict__ xf32,
    const ushort_t* __restrict__ Wb16F, const float* __restrict__ bvec,
    float* __restrict__ out, ushort_t* __restrict__ xbFo)
{
    __shared__ ushort_t Xl[64 * HLS];   // 9216 B

    const int bx = blockIdx.x;
    const int cx = bx & 7, rr = bx >> 3;        // cx = XCD
    const int my = cx * 16 + (rr & 15);         // token panel (64 tokens)
    const int mx = rr >> 4;                     // n panel (64 dims)

    const int tid  = threadIdx.x;
    const int wv   = tid >> 6;
    const int lane = tid & 63;
    const int wm = wv >> 1, wn = wv & 1;
    const int m0 = my * 64 + wm * 32;
    const int n0 = mx * 64 + wn * 32;
    const int lm = lane & 15, quad = lane >> 4;

    const int tA0 = my * 4 + wm * 2;
    const ushort_t* ax0 = xbFi + (size_t)(tA0 * 15) * 512 + lane * 8;
    const ushort_t* ax1 = ax0 + 15 * 512;
    const int ntg0 = mx * 4 + wn * 2;
    const ushort_t* bw0 = Wb16F + (size_t)(ntg0 * 15) * 512 + lane * 8;
    const ushort_t* bw1 = bw0 + 15 * 512;

    f32x4 acc[2][2];
#pragma unroll
    for (int i = 0; i < 2; ++i)
#pragma unroll
        for (int j = 0; j < 2; ++j) acc[i][j] = (f32x4){0.f, 0.f, 0.f, 0.f};

#pragma unroll 3
    for (int ks = 0; ks < 15; ++ks) {
        bf16x8 a0 = *(const bf16x8*)(ax0 + ks * 512);
        bf16x8 a1 = *(const bf16x8*)(ax1 + ks * 512);
        bf16x8 b0 = *(const bf16x8*)(bw0 + ks * 512);
        bf16x8 b1 = *(const bf16x8*)(bw1 + ks * 512);
        acc[0][0] = MFMA16(a0, b0, acc[0][0], 0, 0, 0);
        acc[0][1] = MFMA16(a0, b1, acc[0][1], 0, 0, 0);
        acc[1][0] = MFMA16(a1, b0, acc[1][0], 0, 0, 0);
        acc[1][1] = MFMA16(a1, b1, acc[1][1], 0, 0, 0);
    }

#pragma unroll
    for (int nt = 0; nt < 2; ++nt) {
        const int n  = n0 + nt * 16 + lm;
        const int nl = wn * 32 + nt * 16 + lm;
        const bool nval = (n < D);
        const float bv = nval ? bvec[n] : 0.f;
#pragma unroll
        for (int mt = 0; mt < 2; ++mt) {
#pragma unroll
            for (int r = 0; r < 4; ++r) {
                const int m  = m0 + mt * 16 + quad * 4 + r;
                const int ml = wm * 32 + mt * 16 + quad * 4 + r;
                float y = acc[mt][nt][r] + bv;
                float g = 1.f / (1.f + __expf(-y));
                float o = 0.f;
                if (nval) {
                    float xo = xf32[(size_t)m * D + n];
                    o = g * fmaxf(y, 0.f) + (1.f - g) * xo;
                    out[(size_t)m * D + n] = o;
                }
                Xl[ml * HLS + nl] = f2b(nval ? o : 0.f);
            }
        }
    }
    __syncthreads();

    // ---- fragment-major emit: 4 token tiles x 2 ks slots ----
#pragma unroll 1
    for (int c = tid; c < 512; c += 256) {
        const int fi = c >> 6, l = c & 63;
        const int tl = fi >> 1, ksl = fi & 1;
        const int ksg = mx * 2 + ksl;
        if (ksg < 15) {
            const int lnp = l & 15, qp = l >> 4;
            bf16x8 v = *(const bf16x8*)&Xl[(tl * 16 + lnp) * HLS + ksl * 32 + qp * 8];
            *(bf16x8*)&xbFo[((size_t)((my * 4 + tl) * 15 + ksg) * 64 + l) * 8] = v;
        }
    }
}

// ---------------- kernel 3: highway layer 2 + attn-prep layer 0 (512 threads, 8 waves) ----------------
__global__ __launch_bounds__(512, 4) void highway2_prep_kernel(
    const ushort_t* __restrict__ xbFi, const float* __restrict__ xf32in,
    const ushort_t* __restrict__ Wb16F, const float* __restrict__ bvec,
    const float* __restrict__ attn_w,                      // layer-0 w1|w2|w3
    float* __restrict__ outf, ushort_t* __restrict__ xbFo,
    ushort_t* __restrict__ xw3F, ushort_t* __restrict__ xTF,
    float* __restrict__ s1g, float* __restrict__ s2g)
{
    __shared__ float Xf[16 * XFS];   // 29184 B

    const int bx  = blockIdx.x;
    const int wid = (bx & 7) * 64 + (bx >> 3);
    const int bh  = wid >> 2, jq = wid & 3;
    const int tt  = wid;                 // global 16-token tile
    const int m0  = tt * 16;
    const int tid = threadIdx.x;
    const int wv  = tid >> 6;            // 0..7
    const int lane = tid & 63;
    const int ln = lane & 15, quad = lane >> 4;

    // ---- MFMA: wave wv owns n-tiles wv*4 .. wv*4+3 (clipped to <30) ----
    const ushort_t* ax = xbFi + (size_t)(tt * 15) * 512 + lane * 8;
    f32x4 acc[4];
#pragma unroll
    for (int t = 0; t < 4; ++t) acc[t] = (f32x4){0.f, 0.f, 0.f, 0.f};

#pragma unroll 1
    for (int ks = 0; ks < 15; ++ks) {
        bf16x8 a = *(const bf16x8*)(ax + ks * 512);
#pragma unroll
        for (int t = 0; t < 4; ++t) {
            const int nt = wv * 4 + t;
            if (nt < 30) {
                bf16x8 b = *(const bf16x8*)&Wb16F[(size_t)(nt * 15 + ks) * 512 + lane * 8];
                acc[t] = MFMA16(a, b, acc[t], 0, 0, 0);
            }
        }
    }

    // ---- highway epilogue: f32 out + LDS staging ----
#pragma unroll
    for (int t = 0; t < 4; ++t) {
        const int nt = wv * 4 + t;
        if (nt >= 30) continue;
        const int n = nt * 16 + ln;
        const bool nval = (n < D);
        const float bv = nval ? bvec[n] : 0.f;
#pragma unroll
        for (int reg = 0; reg < 4; ++reg) {
            const int i = quad * 4 + reg;   // local row
            float y = acc[t][reg] + bv;
            float g = 1.f / (1.f + __expf(-y));
            if (nval) {
                float xo = xf32in[(size_t)(m0 + i) * D + n];
                float o = g * fmaxf(y, 0.f) + (1.f - g) * xo;
                outf[(size_t)(m0 + i) * D + n] = o;
                Xf[i * XFS + n] = o;
            }
        }
    }
    __syncthreads();

    // ---- attn-prep (layer 0) from LDS ----
    const float* wb = attn_w;           // w1 | w2 | w3
    const float* w3 = wb + 2 * D;

    // s1/s2 dots: 2 rows per wave (same per-row order as before)
#pragma unroll 1
    for (int rr = 0; rr < 2; ++rr) {
        const int j = wv * 2 + rr;
        float a1 = 0.f, a2 = 0.f;
#pragma unroll
        for (int t = 0; t < 8; ++t) {
            const int k = lane + t * 64;
            if (k < D) {
                float xv = Xf[j * XFS + k];
                a1 = fmaf(xv, wb[k], a1);
                a2 = fmaf(xv, wb[D + k], a2);
            }
        }
        a1 = wave_sum(a1);
        a2 = wave_sum(a2);
        if (lane == 0) { s1g[m0 + j] = a1; s2g[m0 + j] = a2; }
    }

    // xbF + xw3F fragment emit (f2b on the fly)
#pragma unroll 1
    for (int c = tid; c < 960; c += 512) {
        const int ks = c >> 6, l = c & 63;
        const int lnp = l & 15, qp = l >> 4;
        bf16x8 v, pv;
#pragma unroll
        for (int e = 0; e < 8; ++e) {
            const int k = ks * 32 + qp * 8 + e;
            const float x = (k < D) ? Xf[lnp * XFS + k] : 0.f;
            v[e]  = (short)((k < D) ? f2b(x) : 0);
            pv[e] = (short)f2b((k < D) ? x * w3[k] : 0.f);
        }
        *(bf16x8*)&xbFo[((size_t)(tt * 15 + ks) * 64 + l) * 8] = v;
        *(bf16x8*)&xw3F[(size_t)bh * XFRAG + ((jq * 15 + ks) * 64 + l) * 8] = pv;
    }

    // xTF emit (transpose; same quad-pattern as before)
    {
        const int half = jq >> 1, q0 = (jq & 1) * 2;
#pragma unroll 1
        for (int c = tid; c < 960; c += 512) {
            const int dt = c >> 5, s = c & 31;
            const int qp = q0 + (s >> 4), lnp = s & 15;
            const int d  = dt * 16 + lnp;
            const int jb = (qp & 1) * 8;
            bf16x8 v;
#pragma unroll
            for (int e = 0; e < 8; ++e)
                v[e] = (short)((d < D) ? f2b(Xf[(jb + e) * XFS + d]) : 0);
            *(bf16x8*)&xTF[(size_t)bh * XFRAG + ((dt * 2 + half) * 64 + qp * 16 + lnp) * 8] = v;
        }
    }
}

// ---------------- kernel 4: attn core layer 0 + attn-prep layer 1 (512 threads) ----------------
#define ALS 72

__global__ __launch_bounds__(512, 4) void attn_core_prep_kernel(
    const float* __restrict__ xf32,          // residual (buf0)
    const ushort_t* __restrict__ xF, const ushort_t* __restrict__ xw3F,
    const ushort_t* __restrict__ xTF,
    const float* __restrict__ s1g, const float* __restrict__ s2g,
    const int* __restrict__ q1_len, const int* __restrict__ q2_len,
    const float* __restrict__ attn_b, const float* __restrict__ attn_w,
    ushort_t* __restrict__ xbFo,
    ushort_t* __restrict__ xw3Fo, ushort_t* __restrict__ xTFo,
    float* __restrict__ s1o, float* __restrict__ s2o)
{
    __shared__ float    sc[16][68];    // 4352 B
    __shared__ ushort_t Al[16 * ALS];  // 2304 B
    __shared__ float    Qp[4 * 256];   // 4096 B  (odd-ks QK partials)
    __shared__ float    Af[16 * XFS];  // 29184 B

    const int bx  = blockIdx.x;
    const int wid = (bx & 7) * 64 + (bx >> 3);
    const int bh  = wid >> 2, iq = wid & 3;
    const int branch = bh >> 6, b = bh & 63;
    const int tid  = threadIdx.x;
    const int wv   = tid >> 6;           // 0..7
    const int lane = tid & 63;
    const int ln   = lane & 15, quad = lane >> 4;
    const int i0   = iq * 16;
    const int m0   = bh * 64 + i0;
    const int jt   = wv & 3, hks = wv >> 2;

    // ---- QK^T (layer 0): wave (jt,hks) computes even/odd-ks partial of j-tile jt ----
    const ushort_t* xa = xF   + (size_t)bh * XFRAG + (iq * 15 * 64 + lane) * 8;
    const ushort_t* xb = xw3F + (size_t)bh * XFRAG + (jt * 15 * 64 + lane) * 8;

    f32x4 qa = (f32x4){0.f, 0.f, 0.f, 0.f};
    if (hks == 0) {
#pragma unroll
        for (int ks = 0; ks < 15; ks += 2) {     // even: 0,2,...,14 (8)
            bf16x8 a  = *(const bf16x8*)(xa + ks * 512);
            bf16x8 bq = *(const bf16x8*)(xb + ks * 512);
            qa = MFMA16(a, bq, qa, 0, 0, 0);
        }
    } else {
#pragma unroll
        for (int ks = 1; ks < 15; ks += 2) {     // odd: 1,3,...,13 (7)
            bf16x8 a  = *(const bf16x8*)(xa + ks * 512);
            bf16x8 bq = *(const bf16x8*)(xb + ks * 512);
            qa = MFMA16(a, bq, qa, 0, 0, 0);
        }
        *(f32x4*)&Qp[jt * 256 + lane * 4] = qa;
    }
    __syncthreads();

    const int   len  = (branch ? q2_len : q1_len)[b];
    if (hks == 0) {
        f32x4 qo = *(const f32x4*)&Qp[jt * 256 + lane * 4];
        f32x4 qacc = qa + qo;                    // = qa0 + qa1, exact old order
        const float bias = attn_b[0];
        const int   j    = jt * 16 + ln;
        const float s2v  = s2g[bh * 64 + j];
#pragma unroll
        for (int reg = 0; reg < 4; ++reg) {
            const int i = i0 + quad * 4 + reg;
            float v = qacc[reg] + s1g[bh * 64 + i] + s2v + bias;
            if (j >= len) v = -1e-9f;            // reference's (buggy) mask value
            sc[quad * 4 + reg][j] = v;
        }
    }
    __syncthreads();

    // ---- softmax: 2 rows per wave ----
#pragma unroll
    for (int rr = 0; rr < 2; ++rr) {
        const int r = wv * 2 + rr;
        float v = sc[r][lane];
        float m = v;
#pragma unroll
        for (int o = 32; o; o >>= 1) m = fmaxf(m, __shfl_xor(m, o, 64));
        float ev = __expf(v - m);
        float sm = ev;
#pragma unroll
        for (int o = 32; o; o >>= 1) sm += __shfl_xor(sm, o, 64);
        Al[r * ALS + lane] = f2b(ev * (1.f / sm));
    }
    __syncthreads();

    // ---- AV + residual -> LDS f32 staging ----
    const ushort_t* xTb = xTF + (size_t)bh * XFRAG + lane * 8;
    bf16x8 af0 = *(const bf16x8*)&Al[ln * ALS + quad * 8];
    bf16x8 af1 = *(const bf16x8*)&Al[ln * ALS + quad * 8 + 32];

#pragma unroll 2
    for (int dt = wv; dt < 30; dt += 8) {
        bf16x8 b0 = *(const bf16x8*)(xTb + dt * 1024);
        bf16x8 b1 = *(const bf16x8*)(xTb + dt * 1024 + 512);
        f32x4 acc = (f32x4){0.f, 0.f, 0.f, 0.f};
        acc = MFMA16(af0, b0, acc, 0, 0, 0);
        acc = MFMA16(af1, b1, acc, 0, 0, 0);

        const int d = dt * 16 + ln;
        if (d < D) {
#pragma unroll
            for (int reg = 0; reg < 4; ++reg) {
                const int il = quad * 4 + reg;
                float v = acc[reg] + xf32[(size_t)(m0 + il) * D + d];
                Af[il * XFS + d] = v;
            }
        }
    }
    __syncthreads();

    // ---- attn-prep (layer 1) from LDS ----
    const float* wb1 = attn_w + 3 * D;   // layer-1 w1 | w2 | w3
    const float* w31 = wb1 + 2 * D;

#pragma unroll 1
    for (int rr = 0; rr < 2; ++rr) {
        const int jj = wv * 2 + rr;
        float a1 = 0.f, a2 = 0.f;
#pragma unroll
        for (int t = 0; t < 8; ++t) {
            const int k = lane + t * 64;
            if (k < D) {
                float xv = Af[jj * XFS + k];
                a1 = fmaf(xv, wb1[k], a1);
                a2 = fmaf(xv, wb1[D + k], a2);
            }
        }
        a1 = wave_sum(a1);
        a2 = wave_sum(a2);
        if (lane == 0) { s1o[m0 + jj] = a1; s2o[m0 + jj] = a2; }
    }

#pragma unroll 1
    for (int c = tid; c < 960; c += 512) {
        const int ks = c >> 6, l = c & 63;
        const int lnp = l & 15, qp = l >> 4;
        bf16x8 v, pv;
#pragma unroll
        for (int e = 0; e < 8; ++e) {
            const int k = ks * 32 + qp * 8 + e;
            const float x = (k < D) ? Af[lnp * XFS + k] : 0.f;
            v[e]  = (short)((k < D) ? f2b(x) : 0);
            pv[e] = (short)f2b((k < D) ? x * w31[k] : 0.f);
        }
        *(bf16x8*)&xbFo[((size_t)((bh * 4 + iq) * 15 + ks) * 64 + l) * 8] = v;
        *(bf16x8*)&xw3Fo[(size_t)bh * XFRAG + ((iq * 15 + ks) * 64 + l) * 8] = pv;
    }

    {
        const int half = iq >> 1, q0 = (iq & 1) * 2;
#pragma unroll 1
        for (int c = tid; c < 960; c += 512) {
            const int dt = c >> 5, s = c & 31;
            const int qp = q0 + (s >> 4), lnp = s & 15;
            const int d  = dt * 16 + lnp;
            const int jb = (qp & 1) * 8;
            bf16x8 v;
#pragma unroll
            for (int e = 0; e < 8; ++e)
                v[e] = (short)((d < D) ? f2b(Af[(jb + e) * XFS + d]) : 0);
            *(bf16x8*)&xTFo[(size_t)bh * XFRAG + ((dt * 2 + half) * 64 + qp * 16 + lnp) * 8] = v;
        }
    }
}

// ---------------- kernel 5: attn core layer 1 -> final output (512 threads) ----------------
__global__ __launch_bounds__(512, 4) void attn_core_final_kernel(
    const ushort_t* __restrict__ xF, const ushort_t* __restrict__ xw3F,
    const ushort_t* __restrict__ xTF,
    const float* __restrict__ s1g, const float* __restrict__ s2g,
    const int* __restrict__ q1_len, const int* __restrict__ q2_len,
    const float* __restrict__ attn_b,
    float* __restrict__ outf)
{
    __shared__ float    sc[16][68];
    __shared__ ushort_t Al[16 * ALS];
    __shared__ float    Qp[4 * 256];

    const int bx  = blockIdx.x;
    const int wid = (bx & 7) * 64 + (bx >> 3);
    const int bh  = wid >> 2, iq = wid & 3;
    const int branch = bh >> 6, b = bh & 63;
    const int tid  = threadIdx.x;
    const int wv   = tid >> 6;
    const int lane = tid & 63;
    const int ln   = lane & 15, quad = lane >> 4;
    const int i0   = iq * 16;
    const int jt   = wv & 3, hks = wv >> 2;

    const ushort_t* xa = xF   + (size_t)bh * XFRAG + (iq * 15 * 64 + lane) * 8;
    const ushort_t* xb = xw3F + (size_t)bh * XFRAG + (jt * 15 * 64 + lane) * 8;

    f32x4 qa = (f32x4){0.f, 0.f, 0.f, 0.f};
    if (hks == 0) {
#pragma unroll
        for (int ks = 0; ks < 15; ks += 2) {
            bf16x8 a  = *(const bf16x8*)(xa + ks * 512);
            bf16x8 bq = *(const bf16x8*)(xb + ks * 512);
            qa = MFMA16(a, bq, qa, 0, 0, 0);
        }
    } else {
#pragma unroll
        for (int ks = 1; ks < 15; ks += 2) {
            bf16x8 a  = *(const bf16x8*)(xa + ks * 512);
            bf16x8 bq = *(const bf16x8*)(xb + ks * 512);
            qa = MFMA16(a, bq, qa, 0, 0, 0);
        }
        *(f32x4*)&Qp[jt * 256 + lane * 4] = qa;
    }
    __syncthreads();

    const int len = (branch ? q2_len : q1_len)[b];
    if (hks == 0) {
        f32x4 qo = *(const f32x4*)&Qp[jt * 256 + lane * 4];
        f32x4 qacc = qa + qo;
        const float bias = attn_b[1];
        const int   j    = jt * 16 + ln;
        const float s2v  = s2g[bh * 64 + j];
#pragma unroll
        for (int reg = 0; reg < 4; ++reg) {
            const int i = i0 + quad * 4 + reg;
            float v = qacc[reg] + s1g[bh * 64 + i] + s2v + bias;
            if (j >= len) v = -1e-9f;
            sc[quad * 4 + reg][j] = v;
        }
    }
    __syncthreads();

#pragma unroll
    for (int rr = 0; rr < 2; ++rr) {
        const int r = wv * 2 + rr;
        float v = sc[r][lane];
        float m = v;
#pragma unroll
        for (int o = 32; o; o >>= 1) m = fmaxf(m, __shfl_xor(m, o, 64));
        float ev = __expf(v - m);
        float sm = ev;
#pragma unroll
        for (int o = 32; o; o >>= 1) sm += __shfl_xor(sm, o, 64);
        Al[r * ALS + lane] = f2b(ev * (1.f / sm));
    }
    __syncthreads();

    const ushort_t* xTb = xTF + (size_t)bh * XFRAG + lane * 8;
    bf16x8 af0 = *(const bf16x8*)&Al[ln * ALS + quad * 8];
    bf16x8 af1 = *(const bf16x8*)&Al[ln * ALS + quad * 8 + 32];

#pragma unroll 2
    for (int dt = wv; dt < 30; dt += 8) {
        bf16x8 b0 = *(const bf16x8*)(xTb + dt * 1024);
        bf16x8 b1 = *(const bf16x8*)(xTb + dt * 1024 + 512);
        f32x4 acc = (f32x4){0.f, 0.f, 0.f, 0.f};
        acc = MFMA16(af0, b0, acc, 0, 0, 0);
        acc = MFMA16(af1, b1, acc, 0, 0, 0);

        const int d = dt * 16 + ln;
        if (d < D) {
#pragma unroll
            for (int reg = 0; reg < 4; ++reg) {
                const int i = i0 + quad * 4 + reg;
                outf[((size_t)bh * 64 + i) * D + d] = acc[reg];
            }
        }
    }
}

// ---------------- launch ----------------
extern "C" void kernel_launch(void* const* d_in, const int* in_sizes, int n_in,
                              void* d_out, int out_size, void* d_ws, size_t ws_size,
                              hipStream_t stream) {
    const int*   q1       = (const int*)  d_in[0];
    const int*   q2       = (const int*)  d_in[1];
    const int*   q1_len   = (const int*)  d_in[2];
    const int*   q2_len   = (const int*)  d_in[3];
    const int*   q1c      = (const int*)  d_in[4];
    const int*   q2c      = (const int*)  d_in[5];
    const float* word_emb = (const float*)d_in[6];
    const float* char_emb = (const float*)d_in[7];
    const float* w3       = (const float*)d_in[8];
    const float* b3       = (const float*)d_in[9];
    const float* w4       = (const float*)d_in[10];
    const float* b4       = (const float*)d_in[11];
    const float* w5       = (const float*)d_in[12];
    const float* b5       = (const float*)d_in[13];
    const float* hw_w     = (const float*)d_in[14];
    const float* hw_b     = (const float*)d_in[15];
    const float* attn_w   = (const float*)d_in[16];
    const float* attn_b   = (const float*)d_in[17];
    float* out = (float*)d_out;

    float*    buf0    = (float*)d_ws;                          // 2*NT*D f32
    float*    buf1    = buf0 + (size_t)2 * NT * D;             // 2*NT*D f32
    float*    bias160 = buf1 + (size_t)2 * NT * D;             // 160 f32
    ushort_t* xbFa    = (ushort_t*)(bias160 + 160);            // 2*NT*DP bf16 (fragment-major)
    ushort_t* xbFb    = xbFa + (size_t)2 * NT * DP;            // 2*NT*DP bf16
    ushort_t* Wb16F   = xbFb + (size_t)2 * NT * DP;            // WBF_N bf16
    ushort_t* WpadF   = Wb16F + (size_t)WBF_N;                 // WPF_N bf16
    ushort_t* ceb16   = WpadF + (size_t)WPF_N;                 // 100*64 bf16
    ushort_t* xw3Fa   = ceb16 + (size_t)100 * 64;              // NBH*XFRAG bf16
    ushort_t* xTFa    = xw3Fa + (size_t)NBH * XFRAG;           // NBH*XFRAG bf16
    ushort_t* xw3Fb   = xTFa  + (size_t)NBH * XFRAG;           // NBH*XFRAG bf16
    ushort_t* xTFb    = xw3Fb + (size_t)NBH * XFRAG;           // NBH*XFRAG bf16
    float*    s1a     = (float*)(xTFb + (size_t)NBH * XFRAG);  // 2*NT f32
    float*    s2a     = s1a + (size_t)2 * NT;
    float*    s1b     = s2a + (size_t)2 * NT;
    float*    s2b     = s1b + (size_t)2 * NT;

    // 1. weight prep + fused embed/conv -> buf0 + xbFa
    prep_kernel<<<(WBF_N + WPF_N + 160 + 100 * 64 + 255) / 256, 256, 0, stream>>>(
        hw_w, w3, b3, w4, b4, w5, b5, char_emb, Wb16F, WpadF, bias160, ceb16);
    embed_conv_kernel<<<1024, 256, 0, stream>>>(q1, q2, q1c, q2c, word_emb, ceb16,
                                                WpadF, bias160, buf0, xbFa);

    // 2. highway layer 1 (64x64 tiles)
    highway_mfma_kernel<<<1024, 256, 0, stream>>>(xbFa, buf0, Wb16F, hw_b, buf1, xbFb);

    // 3. highway layer 2 + attn-prep layer 0 (512-thread blocks, 16 waves/CU)
    highway2_prep_kernel<<<512, 512, 0, stream>>>(
        xbFb, buf1, Wb16F, hw_b, attn_w, buf0, xbFa, xw3Fa, xTFa, s1a, s2a);

    // 4. attn core layer 0 + attn-prep layer 1 (512-thread blocks)
    attn_core_prep_kernel<<<512, 512, 0, stream>>>(
        buf0, xbFa, xw3Fa, xTFa, s1a, s2a, q1_len, q2_len, attn_b, attn_w,
        xbFb, xw3Fb, xTFb, s1b, s2b);

    // 5. attn core layer 1 -> out (512-thread blocks)
    attn_core_final_kernel<<<512, 512, 0, stream>>>(
        xbFb, xw3Fb, xTFb, s1b, s2b, q1_len, q2_len, attn_b, out);
}

// Round 9
// 283.488 us; speedup vs baseline: 1.1428x; 1.0792x over previous
//
#include <hip/hip_runtime.h>
#include <math.h>

// ---- problem constants ----
#define B   64
#define L   64
#define C   16
#define CHD 64
#define EMB 300
#define D   450       // EMB + 3*50
#define DP  480       // padded bf16 dim count
#define NT  (B*L)     // 4096 tokens per branch
#define NBH 128       // 2 branches * 64 batch

typedef short bf16x8 __attribute__((ext_vector_type(8)));
typedef float f32x4  __attribute__((ext_vector_type(4)));
typedef unsigned short ushort_t;

#define MFMA16 __builtin_amdgcn_mfma_f32_16x16x32_bf16

// fragment-major sizes
#define WPF_N (10 * 10 * 512)           // WpadF: 10 nt x 10 ks x 64 lane x 8
#define WBF_N (32 * 15 * 512)           // Wb16F: 32 nt x 15 ks x 64 lane x 8
#define XFRAG 30720                     // per-bh: 4 tiles x 15 ks x 512 (= 64 tok x 480)

#define XFS 457   // f32 row-staging stride (odd: breaks 16-way LDS bank conflicts)

// ---------------- helpers ----------------
__device__ inline float wave_sum(float v) {
#pragma unroll
    for (int o = 32; o; o >>= 1) v += __shfl_xor(v, o, 64);
    return v;
}
__device__ inline ushort_t f2b(float f) {   // RNE float->bf16
    union { float f; unsigned u; } c; c.f = f;
    unsigned r = c.u + 0x7FFFu + ((c.u >> 16) & 1u);
    return (ushort_t)(r >> 16);
}

// ---------------- kernel P: fused weight prep (fragment-major images) ----------------
__global__ __launch_bounds__(256) void prep_kernel(
    const float* __restrict__ W,
    const float* __restrict__ w3, const float* __restrict__ b3,
    const float* __restrict__ w4, const float* __restrict__ b4,
    const float* __restrict__ w5, const float* __restrict__ b5,
    const float* __restrict__ char_emb,
    ushort_t* __restrict__ Wb16F, ushort_t* __restrict__ WpadF,
    float* __restrict__ bias160, ushort_t* __restrict__ ceb16)
{
    int idx = blockIdx.x * 256 + threadIdx.x;
    if (idx < WBF_N) {   // highway weight fragments
        const int e = idx & 7, l = (idx >> 3) & 63, t = idx >> 9;
        const int ks = t % 15, nt = t / 15;
        const int ln = l & 15, q = l >> 4;
        const int n = nt * 16 + ln, k = ks * 32 + q * 8 + e;
        float v = (n < D && k < D) ? W[(size_t)n * D + k] : 0.f;
        Wb16F[idx] = f2b(v);
        return;
    }
    idx -= WBF_N;
    if (idx < WPF_N) {   // conv weight fragments
        const int e = idx & 7, l = (idx >> 3) & 63, t = idx >> 9;
        const int ks = t % 10, nt = t / 10;
        const int ln = l & 15, q = l >> 4;
        const int f = nt * 16 + ln;
        const int kd = ks * 32 + q * 8 + e;
        const int k = kd >> 6, d = kd & 63;
        float v = 0.f;
        if (f < 50)       { if (k < 3) v = w3[f * 192 + d * 3 + k]; }
        else if (f < 100) { if (k < 4) v = w4[(f - 50) * 256 + d * 4 + k]; }
        else if (f < 150) { v = w5[(f - 100) * 320 + d * 5 + k]; }
        WpadF[idx] = f2b(v);
        return;
    }
    idx -= WPF_N;
    if (idx < 160) {
        bias160[idx] = (idx < 50) ? b3[idx] : (idx < 100) ? b4[idx - 50]
                     : (idx < 150) ? b5[idx - 100] : 0.f;
    } else if (idx < 160 + 100 * 64) {
        int i = idx - 160;
        ceb16[i] = f2b(char_emb[i]);
    }
}

// ---------------- kernel 1: megafront = embed + conv + highway1 + highway2 + attn-prep0 ----------------
// one block per 16-token tile (grid 512, XCD-affine), 512 threads (8 waves).
// X lives in LDS f32 for the whole front; x0/x1 never touch global.
#define ESS 72
#define EST (20 * ESS)

__global__ __launch_bounds__(512, 4) void megafront_kernel(
    const int* __restrict__ q1, const int* __restrict__ q2,
    const int* __restrict__ q1c, const int* __restrict__ q2c,
    const float* __restrict__ word_emb, const ushort_t* __restrict__ ceb16,
    const ushort_t* __restrict__ WpadF, const float* __restrict__ bias160,
    const ushort_t* __restrict__ Wb16F, const float* __restrict__ hw_b,
    const float* __restrict__ attn_w,                      // layer-0 w1|w2|w3
    float* __restrict__ outf, ushort_t* __restrict__ xbFo,
    ushort_t* __restrict__ xw3F, ushort_t* __restrict__ xTF,
    float* __restrict__ s1g, float* __restrict__ s2g)
{
    __shared__ ushort_t es[16 * EST];   // 46080 B (f32 smf overlay after conv)
    __shared__ float    Xf[16 * XFS];   // 29248 B — the resident X tile

    const int bx  = blockIdx.x;
    const int wid = (bx & 7) * 64 + (bx >> 3);   // XCD-affine tile id
    const int bh  = wid >> 2, jq = wid & 3;
    const int tt  = wid;
    const int m0  = tt * 16;                     // global token base
    const int tid = threadIdx.x;
    const int wv  = tid >> 6;                    // 0..7
    const int lane = tid & 63;
    const int ln = lane & 15, quad = lane >> 4;

    // ---- phase A: char-embedding gather for 16 tokens ----
#pragma unroll
    for (int i = 0; i < 4; ++i) {
        int c = tid + i * 512;
        int row = c >> 3, part = c & 7;
        int tl = row >> 4, cr = row & 15;
        int gtok   = m0 + tl;
        int branch = gtok >> 12;
        int tokl   = gtok & (NT - 1);
        int cid    = (branch ? q2c : q1c)[tokl * C + cr];
        *(bf16x8*)&es[tl * EST + cr * ESS + part * 8] =
            *(const bf16x8*)&ceb16[cid * 64 + part * 8];
    }
    {   // zero the 4 pad rows per token (exactly 512 slots)
        int tl = tid >> 5, rr = (tid >> 3) & 3, part = tid & 7;
        bf16x8 z = {0, 0, 0, 0, 0, 0, 0, 0};
        *(bf16x8*)&es[tl * EST + (16 + rr) * ESS + part * 8] = z;
    }

    // ---- phase B: word-embedding copy -> Xf f32 (no global write) ----
#pragma unroll 1
    for (int c = tid; c < 16 * 75; c += 512) {
        const int t  = c / 75, d4 = c - t * 75;
        const int gtok   = m0 + t;
        const int branch = gtok >> 12;
        const int tokl   = gtok & (NT - 1);
        const int w      = (branch ? q2 : q1)[tokl];
        const float4 v = *(const float4*)(word_emb + (size_t)w * EMB + d4 * 4);
        float* dst = &Xf[t * XFS + d4 * 4];
        dst[0] = v.x; dst[1] = v.y; dst[2] = v.z; dst[3] = v.w;
    }
    __syncthreads();

    // ---- phase C: char conv via MFMA (A from es, B from WpadF) ----
    {
        const int t0 = wv * 2, t1 = t0 + 1;
        f32x4 acc[2][10];
#pragma unroll
        for (int t = 0; t < 2; ++t)
#pragma unroll
            for (int nt = 0; nt < 10; ++nt) acc[t][nt] = (f32x4){0.f, 0.f, 0.f, 0.f};

#pragma unroll 1
        for (int ks = 0; ks < 10; ++ks) {
            const int kk   = ks * 32 + quad * 8;
            const int arow = kk >> 6, aoff = kk & 63;
            bf16x8 a0 = *(const bf16x8*)&es[t0 * EST + (ln + arow) * ESS + aoff];
            bf16x8 a1 = *(const bf16x8*)&es[t1 * EST + (ln + arow) * ESS + aoff];
#pragma unroll
            for (int nt = 0; nt < 10; ++nt) {
                bf16x8 bf = *(const bf16x8*)&WpadF[(size_t)((nt * 10 + ks) << 9) + lane * 8];
                acc[0][nt] = MFMA16(a0, bf, acc[0][nt], 0, 0, 0);
                acc[1][nt] = MFMA16(a1, bf, acc[1][nt], 0, 0, 0);
            }
        }
        __syncthreads();   // es reads done; reuse as f32 smf

        float* smf = (float*)es;   // [16][160] f32
#pragma unroll
        for (int t = 0; t < 2; ++t) {
            const int tloc = t0 + t;
#pragma unroll
            for (int nt = 0; nt < 10; ++nt) {
                const int f  = nt * 16 + ln;
                const int Pf = (f < 50) ? 14 : (f < 100) ? 13 : 12;
                float m = -1e30f;
#pragma unroll
                for (int r = 0; r < 4; ++r) {
                    const int p = quad * 4 + r;
                    if (p < Pf) m = fmaxf(m, acc[t][nt][r]);
                }
                m = fmaxf(m, __shfl_xor(m, 16, 64));
                m = fmaxf(m, __shfl_xor(m, 32, 64));
                if (quad == 0) smf[tloc * 160 + f] = fmaxf(0.f, m + bias160[f]);
            }
        }
        __syncthreads();
#pragma unroll 1
        for (int c = tid; c < 16 * 150; c += 512) {
            const int t = c / 150, f = c - t * 150;
            Xf[t * XFS + EMB + f] = smf[t * 160 + f];
        }
    }
    __syncthreads();

    // ---- phase D: highway x2, X in place (A-fragments = f2b(Xf) on the fly) ----
#pragma unroll 1
    for (int h = 0; h < 2; ++h) {
        f32x4 hacc[4];
#pragma unroll
        for (int t = 0; t < 4; ++t) hacc[t] = (f32x4){0.f, 0.f, 0.f, 0.f};

#pragma unroll 1
        for (int ks = 0; ks < 15; ++ks) {
            bf16x8 a;
#pragma unroll
            for (int e = 0; e < 8; ++e) {
                const int k = ks * 32 + quad * 8 + e;
                a[e] = (short)((k < D) ? f2b(Xf[ln * XFS + k]) : 0);
            }
#pragma unroll
            for (int t = 0; t < 4; ++t) {
                const int nt = wv * 4 + t;
                if (nt < 30) {
                    bf16x8 b = *(const bf16x8*)&Wb16F[(size_t)(nt * 15 + ks) * 512 + lane * 8];
                    hacc[t] = MFMA16(a, b, hacc[t], 0, 0, 0);
                }
            }
        }
        __syncthreads();   // all A reads of this layer done before in-place write

#pragma unroll
        for (int t = 0; t < 4; ++t) {
            const int nt = wv * 4 + t;
            if (nt >= 30) continue;
            const int n = nt * 16 + ln;
            if (n < D) {
                const float bv = hw_b[n];
#pragma unroll
                for (int reg = 0; reg < 4; ++reg) {
                    const int i = quad * 4 + reg;
                    float y = hacc[t][reg] + bv;
                    float g = 1.f / (1.f + __expf(-y));
                    float xo = Xf[i * XFS + n];
                    float o = g * fmaxf(y, 0.f) + (1.f - g) * xo;
                    Xf[i * XFS + n] = o;
                    if (h == 1) outf[(size_t)(m0 + i) * D + n] = o;   // x2 f32 (attn residual)
                }
            }
        }
        __syncthreads();
    }

    // ---- phase E: attn-prep layer 0 from Xf (x2) ----
    const float* wb = attn_w;           // w1 | w2 | w3
    const float* w3 = wb + 2 * D;

    // s1/s2 dots: 2 rows per wave (per-row order identical to before)
#pragma unroll 1
    for (int rr = 0; rr < 2; ++rr) {
        const int j = wv * 2 + rr;
        float a1 = 0.f, a2 = 0.f;
#pragma unroll
        for (int t = 0; t < 8; ++t) {
            const int k = lane + t * 64;
            if (k < D) {
                float xv = Xf[j * XFS + k];
                a1 = fmaf(xv, wb[k], a1);
                a2 = fmaf(xv, wb[D + k], a2);
            }
        }
        a1 = wave_sum(a1);
        a2 = wave_sum(a2);
        if (lane == 0) { s1g[m0 + j] = a1; s2g[m0 + j] = a2; }
    }

    // xbF + xw3F fragment emit (f2b on the fly)
#pragma unroll 1
    for (int c = tid; c < 960; c += 512) {
        const int ks = c >> 6, l = c & 63;
        const int lnp = l & 15, qp = l >> 4;
        bf16x8 v, pv;
#pragma unroll
        for (int e = 0; e < 8; ++e) {
            const int k = ks * 32 + qp * 8 + e;
            const float x = (k < D) ? Xf[lnp * XFS + k] : 0.f;
            v[e]  = (short)((k < D) ? f2b(x) : 0);
            pv[e] = (short)f2b((k < D) ? x * w3[k] : 0.f);
        }
        *(bf16x8*)&xbFo[((size_t)(tt * 15 + ks) * 64 + l) * 8] = v;
        *(bf16x8*)&xw3F[(size_t)bh * XFRAG + ((jq * 15 + ks) * 64 + l) * 8] = pv;
    }

    // xTF emit (transpose; quad-pattern unchanged)
    {
        const int half = jq >> 1, q0 = (jq & 1) * 2;
#pragma unroll 1
        for (int c = tid; c < 960; c += 512) {
            const int dt = c >> 5, s = c & 31;
            const int qp = q0 + (s >> 4), lnp = s & 15;
            const int d  = dt * 16 + lnp;
            const int jb = (qp & 1) * 8;
            bf16x8 v;
#pragma unroll
            for (int e = 0; e < 8; ++e)
                v[e] = (short)((d < D) ? f2b(Xf[(jb + e) * XFS + d]) : 0);
            *(bf16x8*)&xTF[(size_t)bh * XFRAG + ((dt * 2 + half) * 64 + qp * 16 + lnp) * 8] = v;
        }
    }
}

// ---------------- kernel 2: attn core layer 0 + attn-prep layer 1 (512 threads) ----------------
#define ALS 72

__global__ __launch_bounds__(512, 4) void attn_core_prep_kernel(
    const float* __restrict__ xf32,          // residual (buf0 = x2)
    const ushort_t* __restrict__ xF, const ushort_t* __restrict__ xw3F,
    const ushort_t* __restrict__ xTF,
    const float* __restrict__ s1g, const float* __restrict__ s2g,
    const int* __restrict__ q1_len, const int* __restrict__ q2_len,
    const float* __restrict__ attn_b, const float* __restrict__ attn_w,
    ushort_t* __restrict__ xbFo,
    ushort_t* __restrict__ xw3Fo, ushort_t* __restrict__ xTFo,
    float* __restrict__ s1o, float* __restrict__ s2o)
{
    __shared__ float    sc[16][68];    // 4352 B
    __shared__ ushort_t Al[16 * ALS];  // 2304 B
    __shared__ float    Qp[4 * 256];   // 4096 B  (odd-ks QK partials)
    __shared__ float    Af[16 * XFS];  // 29248 B

    const int bx  = blockIdx.x;
    const int wid = (bx & 7) * 64 + (bx >> 3);
    const int bh  = wid >> 2, iq = wid & 3;
    const int branch = bh >> 6, b = bh & 63;
    const int tid  = threadIdx.x;
    const int wv   = tid >> 6;           // 0..7
    const int lane = tid & 63;
    const int ln   = lane & 15, quad = lane >> 4;
    const int i0   = iq * 16;
    const int m0   = bh * 64 + i0;
    const int jt   = wv & 3, hks = wv >> 2;

    // ---- QK^T (layer 0): wave (jt,hks) computes even/odd-ks partial of j-tile jt ----
    const ushort_t* xa = xF   + (size_t)bh * XFRAG + (iq * 15 * 64 + lane) * 8;
    const ushort_t* xb = xw3F + (size_t)bh * XFRAG + (jt * 15 * 64 + lane) * 8;

    f32x4 qa = (f32x4){0.f, 0.f, 0.f, 0.f};
    if (hks == 0) {
#pragma unroll
        for (int ks = 0; ks < 15; ks += 2) {     // even: 0,2,...,14 (8)
            bf16x8 a  = *(const bf16x8*)(xa + ks * 512);
            bf16x8 bq = *(const bf16x8*)(xb + ks * 512);
            qa = MFMA16(a, bq, qa, 0, 0, 0);
        }
    } else {
#pragma unroll
        for (int ks = 1; ks < 15; ks += 2) {     // odd: 1,3,...,13 (7)
            bf16x8 a  = *(const bf16x8*)(xa + ks * 512);
            bf16x8 bq = *(const bf16x8*)(xb + ks * 512);
            qa = MFMA16(a, bq, qa, 0, 0, 0);
        }
        *(f32x4*)&Qp[jt * 256 + lane * 4] = qa;
    }
    __syncthreads();

    const int   len  = (branch ? q2_len : q1_len)[b];
    if (hks == 0) {
        f32x4 qo = *(const f32x4*)&Qp[jt * 256 + lane * 4];
        f32x4 qacc = qa + qo;                    // = qa0 + qa1, exact old order
        const float bias = attn_b[0];
        const int   j    = jt * 16 + ln;
        const float s2v  = s2g[bh * 64 + j];
#pragma unroll
        for (int reg = 0; reg < 4; ++reg) {
            const int i = i0 + quad * 4 + reg;
            float v = qacc[reg] + s1g[bh * 64 + i] + s2v + bias;
            if (j >= len) v = -1e-9f;            // reference's (buggy) mask value
            sc[quad * 4 + reg][j] = v;
        }
    }
    __syncthreads();

    // ---- softmax: 2 rows per wave ----
#pragma unroll
    for (int rr = 0; rr < 2; ++rr) {
        const int r = wv * 2 + rr;
        float v = sc[r][lane];
        float m = v;
#pragma unroll
        for (int o = 32; o; o >>= 1) m = fmaxf(m, __shfl_xor(m, o, 64));
        float ev = __expf(v - m);
        float sm = ev;
#pragma unroll
        for (int o = 32; o; o >>= 1) sm += __shfl_xor(sm, o, 64);
        Al[r * ALS + lane] = f2b(ev * (1.f / sm));
    }
    __syncthreads();

    // ---- AV + residual -> LDS f32 staging ----
    const ushort_t* xTb = xTF + (size_t)bh * XFRAG + lane * 8;
    bf16x8 af0 = *(const bf16x8*)&Al[ln * ALS + quad * 8];
    bf16x8 af1 = *(const bf16x8*)&Al[ln * ALS + quad * 8 + 32];

#pragma unroll 2
    for (int dt = wv; dt < 30; dt += 8) {
        bf16x8 b0 = *(const bf16x8*)(xTb + dt * 1024);
        bf16x8 b1 = *(const bf16x8*)(xTb + dt * 1024 + 512);
        f32x4 acc = (f32x4){0.f, 0.f, 0.f, 0.f};
        acc = MFMA16(af0, b0, acc, 0, 0, 0);
        acc = MFMA16(af1, b1, acc, 0, 0, 0);

        const int d = dt * 16 + ln;
        if (d < D) {
#pragma unroll
            for (int reg = 0; reg < 4; ++reg) {
                const int il = quad * 4 + reg;
                float v = acc[reg] + xf32[(size_t)(m0 + il) * D + d];
                Af[il * XFS + d] = v;
            }
        }
    }
    __syncthreads();

    // ---- attn-prep (layer 1) from LDS ----
    const float* wb1 = attn_w + 3 * D;   // layer-1 w1 | w2 | w3
    const float* w31 = wb1 + 2 * D;

#pragma unroll 1
    for (int rr = 0; rr < 2; ++rr) {
        const int jj = wv * 2 + rr;
        float a1 = 0.f, a2 = 0.f;
#pragma unroll
        for (int t = 0; t < 8; ++t) {
            const int k = lane + t * 64;
            if (k < D) {
                float xv = Af[jj * XFS + k];
                a1 = fmaf(xv, wb1[k], a1);
                a2 = fmaf(xv, wb1[D + k], a2);
            }
        }
        a1 = wave_sum(a1);
        a2 = wave_sum(a2);
        if (lane == 0) { s1o[m0 + jj] = a1; s2o[m0 + jj] = a2; }
    }

#pragma unroll 1
    for (int c = tid; c < 960; c += 512) {
        const int ks = c >> 6, l = c & 63;
        const int lnp = l & 15, qp = l >> 4;
        bf16x8 v, pv;
#pragma unroll
        for (int e = 0; e < 8; ++e) {
            const int k = ks * 32 + qp * 8 + e;
            const float x = (k < D) ? Af[lnp * XFS + k] : 0.f;
            v[e]  = (short)((k < D) ? f2b(x) : 0);
            pv[e] = (short)f2b((k < D) ? x * w31[k] : 0.f);
        }
        *(bf16x8*)&xbFo[((size_t)((bh * 4 + iq) * 15 + ks) * 64 + l) * 8] = v;
        *(bf16x8*)&xw3Fo[(size_t)bh * XFRAG + ((iq * 15 + ks) * 64 + l) * 8] = pv;
    }

    {
        const int half = iq >> 1, q0 = (iq & 1) * 2;
#pragma unroll 1
        for (int c = tid; c < 960; c += 512) {
            const int dt = c >> 5, s = c & 31;
            const int qp = q0 + (s >> 4), lnp = s & 15;
            const int d  = dt * 16 + lnp;
            const int jb = (qp & 1) * 8;
            bf16x8 v;
#pragma unroll
            for (int e = 0; e < 8; ++e)
                v[e] = (short)((d < D) ? f2b(Af[(jb + e) * XFS + d]) : 0);
            *(bf16x8*)&xTFo[(size_t)bh * XFRAG + ((dt * 2 + half) * 64 + qp * 16 + lnp) * 8] = v;
        }
    }
}

// ---------------- kernel 3: attn core layer 1 -> final output (512 threads) ----------------
__global__ __launch_bounds__(512, 4) void attn_core_final_kernel(
    const ushort_t* __restrict__ xF, const ushort_t* __restrict__ xw3F,
    const ushort_t* __restrict__ xTF,
    const float* __restrict__ s1g, const float* __restrict__ s2g,
    const int* __restrict__ q1_len, const int* __restrict__ q2_len,
    const float* __restrict__ attn_b,
    float* __restrict__ outf)
{
    __shared__ float    sc[16][68];
    __shared__ ushort_t Al[16 * ALS];
    __shared__ float    Qp[4 * 256];

    const int bx  = blockIdx.x;
    const int wid = (bx & 7) * 64 + (bx >> 3);
    const int bh  = wid >> 2, iq = wid & 3;
    const int branch = bh >> 6, b = bh & 63;
    const int tid  = threadIdx.x;
    const int wv   = tid >> 6;
    const int lane = tid & 63;
    const int ln   = lane & 15, quad = lane >> 4;
    const int i0   = iq * 16;
    const int jt   = wv & 3, hks = wv >> 2;

    const ushort_t* xa = xF   + (size_t)bh * XFRAG + (iq * 15 * 64 + lane) * 8;
    const ushort_t* xb = xw3F + (size_t)bh * XFRAG + (jt * 15 * 64 + lane) * 8;

    f32x4 qa = (f32x4){0.f, 0.f, 0.f, 0.f};
    if (hks == 0) {
#pragma unroll
        for (int ks = 0; ks < 15; ks += 2) {
            bf16x8 a  = *(const bf16x8*)(xa + ks * 512);
            bf16x8 bq = *(const bf16x8*)(xb + ks * 512);
            qa = MFMA16(a, bq, qa, 0, 0, 0);
        }
    } else {
#pragma unroll
        for (int ks = 1; ks < 15; ks += 2) {
            bf16x8 a  = *(const bf16x8*)(xa + ks * 512);
            bf16x8 bq = *(const bf16x8*)(xb + ks * 512);
            qa = MFMA16(a, bq, qa, 0, 0, 0);
        }
        *(f32x4*)&Qp[jt * 256 + lane * 4] = qa;
    }
    __syncthreads();

    const int len = (branch ? q2_len : q1_len)[b];
    if (hks == 0) {
        f32x4 qo = *(const f32x4*)&Qp[jt * 256 + lane * 4];
        f32x4 qacc = qa + qo;
        const float bias = attn_b[1];
        const int   j    = jt * 16 + ln;
        const float s2v  = s2g[bh * 64 + j];
#pragma unroll
        for (int reg = 0; reg < 4; ++reg) {
            const int i = i0 + quad * 4 + reg;
            float v = qacc[reg] + s1g[bh * 64 + i] + s2v + bias;
            if (j >= len) v = -1e-9f;
            sc[quad * 4 + reg][j] = v;
        }
    }
    __syncthreads();

#pragma unroll
    for (int rr = 0; rr < 2; ++rr) {
        const int r = wv * 2 + rr;
        float v = sc[r][lane];
        float m = v;
#pragma unroll
        for (int o = 32; o; o >>= 1) m = fmaxf(m, __shfl_xor(m, o, 64));
        float ev = __expf(v - m);
        float sm = ev;
#pragma unroll
        for (int o = 32; o; o >>= 1) sm += __shfl_xor(sm, o, 64);
        Al[r * ALS + lane] = f2b(ev * (1.f / sm));
    }
    __syncthreads();

    const ushort_t* xTb = xTF + (size_t)bh * XFRAG + lane * 8;
    bf16x8 af0 = *(const bf16x8*)&Al[ln * ALS + quad * 8];
    bf16x8 af1 = *(const bf16x8*)&Al[ln * ALS + quad * 8 + 32];

#pragma unroll 2
    for (int dt = wv; dt < 30; dt += 8) {
        bf16x8 b0 = *(const bf16x8*)(xTb + dt * 1024);
        bf16x8 b1 = *(const bf16x8*)(xTb + dt * 1024 + 512);
        f32x4 acc = (f32x4){0.f, 0.f, 0.f, 0.f};
        acc = MFMA16(af0, b0, acc, 0, 0, 0);
        acc = MFMA16(af1, b1, acc, 0, 0, 0);

        const int d = dt * 16 + ln;
        if (d < D) {
#pragma unroll
            for (int reg = 0; reg < 4; ++reg) {
                const int i = i0 + quad * 4 + reg;
                outf[((size_t)bh * 64 + i) * D + d] = acc[reg];
            }
        }
    }
}

// ---------------- launch ----------------
extern "C" void kernel_launch(void* const* d_in, const int* in_sizes, int n_in,
                              void* d_out, int out_size, void* d_ws, size_t ws_size,
                              hipStream_t stream) {
    const int*   q1       = (const int*)  d_in[0];
    const int*   q2       = (const int*)  d_in[1];
    const int*   q1_len   = (const int*)  d_in[2];
    const int*   q2_len   = (const int*)  d_in[3];
    const int*   q1c      = (const int*)  d_in[4];
    const int*   q2c      = (const int*)  d_in[5];
    const float* word_emb = (const float*)d_in[6];
    const float* char_emb = (const float*)d_in[7];
    const float* w3       = (const float*)d_in[8];
    const float* b3       = (const float*)d_in[9];
    const float* w4       = (const float*)d_in[10];
    const float* b4       = (const float*)d_in[11];
    const float* w5       = (const float*)d_in[12];
    const float* b5       = (const float*)d_in[13];
    const float* hw_w     = (const float*)d_in[14];
    const float* hw_b     = (const float*)d_in[15];
    const float* attn_w   = (const float*)d_in[16];
    const float* attn_b   = (const float*)d_in[17];
    float* out = (float*)d_out;

    float*    buf0    = (float*)d_ws;                          // 2*NT*D f32 (x2)
    float*    buf1    = buf0 + (size_t)2 * NT * D;             // (unused, layout keep)
    float*    bias160 = buf1 + (size_t)2 * NT * D;             // 160 f32
    ushort_t* xbFa    = (ushort_t*)(bias160 + 160);            // 2*NT*DP bf16 (fragment-major)
    ushort_t* xbFb    = xbFa + (size_t)2 * NT * DP;            // 2*NT*DP bf16
    ushort_t* Wb16F   = xbFb + (size_t)2 * NT * DP;            // WBF_N bf16
    ushort_t* WpadF   = Wb16F + (size_t)WBF_N;                 // WPF_N bf16
    ushort_t* ceb16   = WpadF + (size_t)WPF_N;                 // 100*64 bf16
    ushort_t* xw3Fa   = ceb16 + (size_t)100 * 64;              // NBH*XFRAG bf16
    ushort_t* xTFa    = xw3Fa + (size_t)NBH * XFRAG;           // NBH*XFRAG bf16
    ushort_t* xw3Fb   = xTFa  + (size_t)NBH * XFRAG;           // NBH*XFRAG bf16
    ushort_t* xTFb    = xw3Fb + (size_t)NBH * XFRAG;           // NBH*XFRAG bf16
    float*    s1a     = (float*)(xTFb + (size_t)NBH * XFRAG);  // 2*NT f32
    float*    s2a     = s1a + (size_t)2 * NT;
    float*    s1b     = s2a + (size_t)2 * NT;
    float*    s2b     = s1b + (size_t)2 * NT;

    // 1. weight prep
    prep_kernel<<<(WBF_N + WPF_N + 160 + 100 * 64 + 255) / 256, 256, 0, stream>>>(
        hw_w, w3, b3, w4, b4, w5, b5, char_emb, Wb16F, WpadF, bias160, ceb16);

    // 2. megafront: embed + conv + highway1 + highway2 + attn-prep0
    //    -> buf0 (x2 f32), xbFa, xw3Fa, xTFa, s1a/s2a
    megafront_kernel<<<512, 512, 0, stream>>>(
        q1, q2, q1c, q2c, word_emb, ceb16, WpadF, bias160, Wb16F, hw_b,
        attn_w, buf0, xbFa, xw3Fa, xTFa, s1a, s2a);

    // 3. attn core layer 0 + attn-prep layer 1
    attn_core_prep_kernel<<<512, 512, 0, stream>>>(
        buf0, xbFa, xw3Fa, xTFa, s1a, s2a, q1_len, q2_len, attn_b, attn_w,
        xbFb, xw3Fb, xTFb, s1b, s2b);

    // 4. attn core layer 1 -> out
    attn_core_final_kernel<<<512, 512, 0, stream>>>(
        xbFb, xw3Fb, xTFb, s1b, s2b, q1_len, q2_len, attn_b, out);
}

// Round 10
// 274.611 us; speedup vs baseline: 1.1798x; 1.0323x over previous
//
#include <hip/hip_runtime.h>
#include <math.h>

// ---- problem constants ----
#define B   64
#define L   64
#define C   16
#define CHD 64
#define EMB 300
#define D   450       // EMB + 3*50
#define DP  480       // padded bf16 dim count
#define NT  (B*L)     // 4096 tokens per branch
#define NBH 128       // 2 branches * 64 batch

typedef short bf16x8 __attribute__((ext_vector_type(8)));
typedef float f32x4  __attribute__((ext_vector_type(4)));
typedef unsigned short ushort_t;

#define MFMA16 __builtin_amdgcn_mfma_f32_16x16x32_bf16

// fragment-major sizes
#define WPF_N (10 * 10 * 512)           // WpadF: 10 nt x 10 ks x 64 lane x 8
#define WBF_N (32 * 15 * 512)           // Wb16F: 32 nt x 15 ks x 64 lane x 8
#define XFRAG 30720                     // per-bh: 4 tiles x 15 ks x 512 (= 64 tok x 480)

#define XFS 457   // f32 row-staging stride (odd: breaks 16-way LDS bank conflicts)

// ---------------- helpers ----------------
__device__ inline float wave_sum(float v) {
#pragma unroll
    for (int o = 32; o; o >>= 1) v += __shfl_xor(v, o, 64);
    return v;
}
__device__ inline ushort_t f2b(float f) {   // RNE float->bf16
    union { float f; unsigned u; } c; c.f = f;
    unsigned r = c.u + 0x7FFFu + ((c.u >> 16) & 1u);
    return (ushort_t)(r >> 16);
}

// ---------------- kernel P: fused weight prep (fragment-major images) ----------------
__global__ __launch_bounds__(256) void prep_kernel(
    const float* __restrict__ W,
    const float* __restrict__ w3, const float* __restrict__ b3,
    const float* __restrict__ w4, const float* __restrict__ b4,
    const float* __restrict__ w5, const float* __restrict__ b5,
    const float* __restrict__ char_emb,
    ushort_t* __restrict__ Wb16F, ushort_t* __restrict__ WpadF,
    float* __restrict__ bias160, ushort_t* __restrict__ ceb16)
{
    int idx = blockIdx.x * 256 + threadIdx.x;
    if (idx < WBF_N) {   // highway weight fragments
        const int e = idx & 7, l = (idx >> 3) & 63, t = idx >> 9;
        const int ks = t % 15, nt = t / 15;
        const int ln = l & 15, q = l >> 4;
        const int n = nt * 16 + ln, k = ks * 32 + q * 8 + e;
        float v = (n < D && k < D) ? W[(size_t)n * D + k] : 0.f;
        Wb16F[idx] = f2b(v);
        return;
    }
    idx -= WBF_N;
    if (idx < WPF_N) {   // conv weight fragments
        const int e = idx & 7, l = (idx >> 3) & 63, t = idx >> 9;
        const int ks = t % 10, nt = t / 10;
        const int ln = l & 15, q = l >> 4;
        const int f = nt * 16 + ln;
        const int kd = ks * 32 + q * 8 + e;
        const int k = kd >> 6, d = kd & 63;
        float v = 0.f;
        if (f < 50)       { if (k < 3) v = w3[f * 192 + d * 3 + k]; }
        else if (f < 100) { if (k < 4) v = w4[(f - 50) * 256 + d * 4 + k]; }
        else if (f < 150) { v = w5[(f - 100) * 320 + d * 5 + k]; }
        WpadF[idx] = f2b(v);
        return;
    }
    idx -= WPF_N;
    if (idx < 160) {
        bias160[idx] = (idx < 50) ? b3[idx] : (idx < 100) ? b4[idx - 50]
                     : (idx < 150) ? b5[idx - 100] : 0.f;
    } else if (idx < 160 + 100 * 64) {
        int i = idx - 160;
        ceb16[i] = f2b(char_emb[i]);
    }
}

// ---------------- kernel 1: megafront = embed + conv + highway1 + highway2 + attn-prep0 ----------------
// one block per 16-token tile (grid 512, XCD-affine), 512 threads (8 waves).
// X lives in LDS f32 for the whole front; x0/x1 never touch global.
#define ESS 72
#define EST (20 * ESS)

__global__ __launch_bounds__(512, 4) void megafront_kernel(
    const int* __restrict__ q1, const int* __restrict__ q2,
    const int* __restrict__ q1c, const int* __restrict__ q2c,
    const float* __restrict__ word_emb, const ushort_t* __restrict__ ceb16,
    const ushort_t* __restrict__ WpadF, const float* __restrict__ bias160,
    const ushort_t* __restrict__ Wb16F, const float* __restrict__ hw_b,
    const float* __restrict__ attn_w,                      // layer-0 w1|w2|w3
    float* __restrict__ outf, ushort_t* __restrict__ xbFo,
    ushort_t* __restrict__ xw3F, ushort_t* __restrict__ xTF,
    float* __restrict__ s1g, float* __restrict__ s2g)
{
    __shared__ ushort_t es[16 * EST];   // 46080 B (smf f32 overlay; XbL fragment overlay)
    __shared__ float    Xf[16 * XFS];   // 29248 B — the resident X tile

    const int bx  = blockIdx.x;
    const int wid = (bx & 7) * 64 + (bx >> 3);   // XCD-affine tile id
    const int bh  = wid >> 2, jq = wid & 3;
    const int tt  = wid;
    const int m0  = tt * 16;                     // global token base
    const int tid = threadIdx.x;
    const int wv  = tid >> 6;                    // 0..7
    const int lane = tid & 63;
    const int ln = lane & 15, quad = lane >> 4;

    // ---- phase A: char-embedding gather for 16 tokens ----
#pragma unroll
    for (int i = 0; i < 4; ++i) {
        int c = tid + i * 512;
        int row = c >> 3, part = c & 7;
        int tl = row >> 4, cr = row & 15;
        int gtok   = m0 + tl;
        int branch = gtok >> 12;
        int tokl   = gtok & (NT - 1);
        int cid    = (branch ? q2c : q1c)[tokl * C + cr];
        *(bf16x8*)&es[tl * EST + cr * ESS + part * 8] =
            *(const bf16x8*)&ceb16[cid * 64 + part * 8];
    }
    {   // zero the 4 pad rows per token (exactly 512 slots)
        int tl = tid >> 5, rr = (tid >> 3) & 3, part = tid & 7;
        bf16x8 z = {0, 0, 0, 0, 0, 0, 0, 0};
        *(bf16x8*)&es[tl * EST + (16 + rr) * ESS + part * 8] = z;
    }

    // ---- phase B: word-embedding copy -> Xf f32 (no global write) ----
#pragma unroll 1
    for (int c = tid; c < 16 * 75; c += 512) {
        const int t  = c / 75, d4 = c - t * 75;
        const int gtok   = m0 + t;
        const int branch = gtok >> 12;
        const int tokl   = gtok & (NT - 1);
        const int w      = (branch ? q2 : q1)[tokl];
        const float4 v = *(const float4*)(word_emb + (size_t)w * EMB + d4 * 4);
        float* dst = &Xf[t * XFS + d4 * 4];
        dst[0] = v.x; dst[1] = v.y; dst[2] = v.z; dst[3] = v.w;
    }
    __syncthreads();

    // ---- phase C: char conv via MFMA (A from es, B from WpadF) ----
    {
        const int t0 = wv * 2, t1 = t0 + 1;
        f32x4 acc[2][10];
#pragma unroll
        for (int t = 0; t < 2; ++t)
#pragma unroll
            for (int nt = 0; nt < 10; ++nt) acc[t][nt] = (f32x4){0.f, 0.f, 0.f, 0.f};

#pragma unroll 1
        for (int ks = 0; ks < 10; ++ks) {
            const int kk   = ks * 32 + quad * 8;
            const int arow = kk >> 6, aoff = kk & 63;
            bf16x8 a0 = *(const bf16x8*)&es[t0 * EST + (ln + arow) * ESS + aoff];
            bf16x8 a1 = *(const bf16x8*)&es[t1 * EST + (ln + arow) * ESS + aoff];
#pragma unroll
            for (int nt = 0; nt < 10; ++nt) {
                bf16x8 bf = *(const bf16x8*)&WpadF[(size_t)((nt * 10 + ks) << 9) + lane * 8];
                acc[0][nt] = MFMA16(a0, bf, acc[0][nt], 0, 0, 0);
                acc[1][nt] = MFMA16(a1, bf, acc[1][nt], 0, 0, 0);
            }
        }
        __syncthreads();   // es reads done; reuse as f32 smf

        float* smf = (float*)es;   // [16][160] f32
#pragma unroll
        for (int t = 0; t < 2; ++t) {
            const int tloc = t0 + t;
#pragma unroll
            for (int nt = 0; nt < 10; ++nt) {
                const int f  = nt * 16 + ln;
                const int Pf = (f < 50) ? 14 : (f < 100) ? 13 : 12;
                float m = -1e30f;
#pragma unroll
                for (int r = 0; r < 4; ++r) {
                    const int p = quad * 4 + r;
                    if (p < Pf) m = fmaxf(m, acc[t][nt][r]);
                }
                m = fmaxf(m, __shfl_xor(m, 16, 64));
                m = fmaxf(m, __shfl_xor(m, 32, 64));
                if (quad == 0) smf[tloc * 160 + f] = fmaxf(0.f, m + bias160[f]);
            }
        }
        __syncthreads();
#pragma unroll 1
        for (int c = tid; c < 16 * 150; c += 512) {
            const int t = c / 150, f = c - t * 150;
            Xf[t * XFS + EMB + f] = smf[t * 160 + f];
        }
    }
    __syncthreads();

    // ---- phase D: highway x2; shared A-fragment staging in LDS (reuses es) ----
    ushort_t* XbL = es;   // [15][64][8] bf16 = 15360 B (smf dead)
#pragma unroll 1
    for (int h = 0; h < 2; ++h) {
        // stage bf16 A-fragments of current X ONCE (was: rebuilt per wave)
#pragma unroll 1
        for (int c = tid; c < 960; c += 512) {
            const int ks = c >> 6, l = c & 63;
            const int lnp = l & 15, qp = l >> 4;
            bf16x8 a;
#pragma unroll
            for (int e = 0; e < 8; ++e) {
                const int k = ks * 32 + qp * 8 + e;
                a[e] = (short)((k < D) ? f2b(Xf[lnp * XFS + k]) : 0);
            }
            *(bf16x8*)&XbL[(size_t)c * 8] = a;
        }
        __syncthreads();

        f32x4 hacc[4];
#pragma unroll
        for (int t = 0; t < 4; ++t) hacc[t] = (f32x4){0.f, 0.f, 0.f, 0.f};

#pragma unroll 1
        for (int ks = 0; ks < 15; ++ks) {
            bf16x8 a = *(const bf16x8*)&XbL[(ks * 64 + lane) * 8];   // conflict-free b128
#pragma unroll
            for (int t = 0; t < 4; ++t) {
                const int nt = wv * 4 + t;
                if (nt < 30) {
                    bf16x8 b = *(const bf16x8*)&Wb16F[(size_t)(nt * 15 + ks) * 512 + lane * 8];
                    hacc[t] = MFMA16(a, b, hacc[t], 0, 0, 0);
                }
            }
        }
        __syncthreads();   // staging reads of Xf + XbL reads done before in-place write

#pragma unroll
        for (int t = 0; t < 4; ++t) {
            const int nt = wv * 4 + t;
            if (nt >= 30) continue;
            const int n = nt * 16 + ln;
            if (n < D) {
                const float bv = hw_b[n];
#pragma unroll
                for (int reg = 0; reg < 4; ++reg) {
                    const int i = quad * 4 + reg;
                    float y = hacc[t][reg] + bv;
                    float g = 1.f / (1.f + __expf(-y));
                    float xo = Xf[i * XFS + n];
                    float o = g * fmaxf(y, 0.f) + (1.f - g) * xo;
                    Xf[i * XFS + n] = o;
                    if (h == 1) outf[(size_t)(m0 + i) * D + n] = o;   // x2 f32 (attn residual)
                }
            }
        }
        __syncthreads();
    }

    // ---- phase E: attn-prep layer 0 from Xf (x2) ----
    const float* wb = attn_w;           // w1 | w2 | w3
    const float* w3 = wb + 2 * D;

    // s1/s2 dots: 2 rows per wave (per-row order identical to before)
#pragma unroll 1
    for (int rr = 0; rr < 2; ++rr) {
        const int j = wv * 2 + rr;
        float a1 = 0.f, a2 = 0.f;
#pragma unroll
        for (int t = 0; t < 8; ++t) {
            const int k = lane + t * 64;
            if (k < D) {
                float xv = Xf[j * XFS + k];
                a1 = fmaf(xv, wb[k], a1);
                a2 = fmaf(xv, wb[D + k], a2);
            }
        }
        a1 = wave_sum(a1);
        a2 = wave_sum(a2);
        if (lane == 0) { s1g[m0 + j] = a1; s2g[m0 + j] = a2; }
    }

    // xbF + xw3F fragment emit (f2b on the fly)
#pragma unroll 1
    for (int c = tid; c < 960; c += 512) {
        const int ks = c >> 6, l = c & 63;
        const int lnp = l & 15, qp = l >> 4;
        bf16x8 v, pv;
#pragma unroll
        for (int e = 0; e < 8; ++e) {
            const int k = ks * 32 + qp * 8 + e;
            const float x = (k < D) ? Xf[lnp * XFS + k] : 0.f;
            v[e]  = (short)((k < D) ? f2b(x) : 0);
            pv[e] = (short)f2b((k < D) ? x * w3[k] : 0.f);
        }
        *(bf16x8*)&xbFo[((size_t)(tt * 15 + ks) * 64 + l) * 8] = v;
        *(bf16x8*)&xw3F[(size_t)bh * XFRAG + ((jq * 15 + ks) * 64 + l) * 8] = pv;
    }

    // xTF emit (transpose; quad-pattern unchanged)
    {
        const int half = jq >> 1, q0 = (jq & 1) * 2;
#pragma unroll 1
        for (int c = tid; c < 960; c += 512) {
            const int dt = c >> 5, s = c & 31;
            const int qp = q0 + (s >> 4), lnp = s & 15;
            const int d  = dt * 16 + lnp;
            const int jb = (qp & 1) * 8;
            bf16x8 v;
#pragma unroll
            for (int e = 0; e < 8; ++e)
                v[e] = (short)((d < D) ? f2b(Xf[(jb + e) * XFS + d]) : 0);
            *(bf16x8*)&xTF[(size_t)bh * XFRAG + ((dt * 2 + half) * 64 + qp * 16 + lnp) * 8] = v;
        }
    }
}

// ---------------- kernel 2: attn core layer 0 + attn-prep layer 1 (512 threads) ----------------
#define ALS 72

__global__ __launch_bounds__(512, 4) void attn_core_prep_kernel(
    const float* __restrict__ xf32,          // residual (buf0 = x2)
    const ushort_t* __restrict__ xF, const ushort_t* __restrict__ xw3F,
    const ushort_t* __restrict__ xTF,
    const float* __restrict__ s1g, const float* __restrict__ s2g,
    const int* __restrict__ q1_len, const int* __restrict__ q2_len,
    const float* __restrict__ attn_b, const float* __restrict__ attn_w,
    ushort_t* __restrict__ xbFo,
    ushort_t* __restrict__ xw3Fo, ushort_t* __restrict__ xTFo,
    float* __restrict__ s1o, float* __restrict__ s2o)
{
    __shared__ float    sc[16][68];    // 4352 B
    __shared__ ushort_t Al[16 * ALS];  // 2304 B
    __shared__ float    Qp[4 * 256];   // 4096 B  (odd-ks QK partials)
    __shared__ float    Af[16 * XFS];  // 29248 B

    const int bx  = blockIdx.x;
    const int wid = (bx & 7) * 64 + (bx >> 3);
    const int bh  = wid >> 2, iq = wid & 3;
    const int branch = bh >> 6, b = bh & 63;
    const int tid  = threadIdx.x;
    const int wv   = tid >> 6;           // 0..7
    const int lane = tid & 63;
    const int ln   = lane & 15, quad = lane >> 4;
    const int i0   = iq * 16;
    const int m0   = bh * 64 + i0;
    const int jt   = wv & 3, hks = wv >> 2;

    // ---- QK^T (layer 0): wave (jt,hks) computes even/odd-ks partial of j-tile jt ----
    const ushort_t* xa = xF   + (size_t)bh * XFRAG + (iq * 15 * 64 + lane) * 8;
    const ushort_t* xb = xw3F + (size_t)bh * XFRAG + (jt * 15 * 64 + lane) * 8;

    f32x4 qa = (f32x4){0.f, 0.f, 0.f, 0.f};
    if (hks == 0) {
#pragma unroll
        for (int ks = 0; ks < 15; ks += 2) {     // even: 0,2,...,14 (8)
            bf16x8 a  = *(const bf16x8*)(xa + ks * 512);
            bf16x8 bq = *(const bf16x8*)(xb + ks * 512);
            qa = MFMA16(a, bq, qa, 0, 0, 0);
        }
    } else {
#pragma unroll
        for (int ks = 1; ks < 15; ks += 2) {     // odd: 1,3,...,13 (7)
            bf16x8 a  = *(const bf16x8*)(xa + ks * 512);
            bf16x8 bq = *(const bf16x8*)(xb + ks * 512);
            qa = MFMA16(a, bq, qa, 0, 0, 0);
        }
        *(f32x4*)&Qp[jt * 256 + lane * 4] = qa;
    }
    __syncthreads();

    const int   len  = (branch ? q2_len : q1_len)[b];
    if (hks == 0) {
        f32x4 qo = *(const f32x4*)&Qp[jt * 256 + lane * 4];
        f32x4 qacc = qa + qo;                    // = qa0 + qa1, exact old order
        const float bias = attn_b[0];
        const int   j    = jt * 16 + ln;
        const float s2v  = s2g[bh * 64 + j];
#pragma unroll
        for (int reg = 0; reg < 4; ++reg) {
            const int i = i0 + quad * 4 + reg;
            float v = qacc[reg] + s1g[bh * 64 + i] + s2v + bias;
            if (j >= len) v = -1e-9f;            // reference's (buggy) mask value
            sc[quad * 4 + reg][j] = v;
        }
    }
    __syncthreads();

    // ---- softmax: 2 rows per wave ----
#pragma unroll
    for (int rr = 0; rr < 2; ++rr) {
        const int r = wv * 2 + rr;
        float v = sc[r][lane];
        float m = v;
#pragma unroll
        for (int o = 32; o; o >>= 1) m = fmaxf(m, __shfl_xor(m, o, 64));
        float ev = __expf(v - m);
        float sm = ev;
#pragma unroll
        for (int o = 32; o; o >>= 1) sm += __shfl_xor(sm, o, 64);
        Al[r * ALS + lane] = f2b(ev * (1.f / sm));
    }
    __syncthreads();

    // ---- AV + residual -> LDS f32 staging ----
    const ushort_t* xTb = xTF + (size_t)bh * XFRAG + lane * 8;
    bf16x8 af0 = *(const bf16x8*)&Al[ln * ALS + quad * 8];
    bf16x8 af1 = *(const bf16x8*)&Al[ln * ALS + quad * 8 + 32];

#pragma unroll 2
    for (int dt = wv; dt < 30; dt += 8) {
        bf16x8 b0 = *(const bf16x8*)(xTb + dt * 1024);
        bf16x8 b1 = *(const bf16x8*)(xTb + dt * 1024 + 512);
        f32x4 acc = (f32x4){0.f, 0.f, 0.f, 0.f};
        acc = MFMA16(af0, b0, acc, 0, 0, 0);
        acc = MFMA16(af1, b1, acc, 0, 0, 0);

        const int d = dt * 16 + ln;
        if (d < D) {
#pragma unroll
            for (int reg = 0; reg < 4; ++reg) {
                const int il = quad * 4 + reg;
                float v = acc[reg] + xf32[(size_t)(m0 + il) * D + d];
                Af[il * XFS + d] = v;
            }
        }
    }
    __syncthreads();

    // ---- attn-prep (layer 1) from LDS ----
    const float* wb1 = attn_w + 3 * D;   // layer-1 w1 | w2 | w3
    const float* w31 = wb1 + 2 * D;

#pragma unroll 1
    for (int rr = 0; rr < 2; ++rr) {
        const int jj = wv * 2 + rr;
        float a1 = 0.f, a2 = 0.f;
#pragma unroll
        for (int t = 0; t < 8; ++t) {
            const int k = lane + t * 64;
            if (k < D) {
                float xv = Af[jj * XFS + k];
                a1 = fmaf(xv, wb1[k], a1);
                a2 = fmaf(xv, wb1[D + k], a2);
            }
        }
        a1 = wave_sum(a1);
        a2 = wave_sum(a2);
        if (lane == 0) { s1o[m0 + jj] = a1; s2o[m0 + jj] = a2; }
    }

#pragma unroll 1
    for (int c = tid; c < 960; c += 512) {
        const int ks = c >> 6, l = c & 63;
        const int lnp = l & 15, qp = l >> 4;
        bf16x8 v, pv;
#pragma unroll
        for (int e = 0; e < 8; ++e) {
            const int k = ks * 32 + qp * 8 + e;
            const float x = (k < D) ? Af[lnp * XFS + k] : 0.f;
            v[e]  = (short)((k < D) ? f2b(x) : 0);
            pv[e] = (short)f2b((k < D) ? x * w31[k] : 0.f);
        }
        *(bf16x8*)&xbFo[((size_t)((bh * 4 + iq) * 15 + ks) * 64 + l) * 8] = v;
        *(bf16x8*)&xw3Fo[(size_t)bh * XFRAG + ((iq * 15 + ks) * 64 + l) * 8] = pv;
    }

    {
        const int half = iq >> 1, q0 = (iq & 1) * 2;
#pragma unroll 1
        for (int c = tid; c < 960; c += 512) {
            const int dt = c >> 5, s = c & 31;
            const int qp = q0 + (s >> 4), lnp = s & 15;
            const int d  = dt * 16 + lnp;
            const int jb = (qp & 1) * 8;
            bf16x8 v;
#pragma unroll
            for (int e = 0; e < 8; ++e)
                v[e] = (short)((d < D) ? f2b(Af[(jb + e) * XFS + d]) : 0);
            *(bf16x8*)&xTFo[(size_t)bh * XFRAG + ((dt * 2 + half) * 64 + qp * 16 + lnp) * 8] = v;
        }
    }
}

// ---------------- kernel 3: attn core layer 1 -> final output (512 threads) ----------------
__global__ __launch_bounds__(512, 4) void attn_core_final_kernel(
    const ushort_t* __restrict__ xF, const ushort_t* __restrict__ xw3F,
    const ushort_t* __restrict__ xTF,
    const float* __restrict__ s1g, const float* __restrict__ s2g,
    const int* __restrict__ q1_len, const int* __restrict__ q2_len,
    const float* __restrict__ attn_b,
    float* __restrict__ outf)
{
    __shared__ float    sc[16][68];
    __shared__ ushort_t Al[16 * ALS];
    __shared__ float    Qp[4 * 256];

    const int bx  = blockIdx.x;
    const int wid = (bx & 7) * 64 + (bx >> 3);
    const int bh  = wid >> 2, iq = wid & 3;
    const int branch = bh >> 6, b = bh & 63;
    const int tid  = threadIdx.x;
    const int wv   = tid >> 6;
    const int lane = tid & 63;
    const int ln   = lane & 15, quad = lane >> 4;
    const int i0   = iq * 16;
    const int jt   = wv & 3, hks = wv >> 2;

    const ushort_t* xa = xF   + (size_t)bh * XFRAG + (iq * 15 * 64 + lane) * 8;
    const ushort_t* xb = xw3F + (size_t)bh * XFRAG + (jt * 15 * 64 + lane) * 8;

    f32x4 qa = (f32x4){0.f, 0.f, 0.f, 0.f};
    if (hks == 0) {
#pragma unroll
        for (int ks = 0; ks < 15; ks += 2) {
            bf16x8 a  = *(const bf16x8*)(xa + ks * 512);
            bf16x8 bq = *(const bf16x8*)(xb + ks * 512);
            qa = MFMA16(a, bq, qa, 0, 0, 0);
        }
    } else {
#pragma unroll
        for (int ks = 1; ks < 15; ks += 2) {
            bf16x8 a  = *(const bf16x8*)(xa + ks * 512);
            bf16x8 bq = *(const bf16x8*)(xb + ks * 512);
            qa = MFMA16(a, bq, qa, 0, 0, 0);
        }
        *(f32x4*)&Qp[jt * 256 + lane * 4] = qa;
    }
    __syncthreads();

    const int len = (branch ? q2_len : q1_len)[b];
    if (hks == 0) {
        f32x4 qo = *(const f32x4*)&Qp[jt * 256 + lane * 4];
        f32x4 qacc = qa + qo;
        const float bias = attn_b[1];
        const int   j    = jt * 16 + ln;
        const float s2v  = s2g[bh * 64 + j];
#pragma unroll
        for (int reg = 0; reg < 4; ++reg) {
            const int i = i0 + quad * 4 + reg;
            float v = qacc[reg] + s1g[bh * 64 + i] + s2v + bias;
            if (j >= len) v = -1e-9f;
            sc[quad * 4 + reg][j] = v;
        }
    }
    __syncthreads();

#pragma unroll
    for (int rr = 0; rr < 2; ++rr) {
        const int r = wv * 2 + rr;
        float v = sc[r][lane];
        float m = v;
#pragma unroll
        for (int o = 32; o; o >>= 1) m = fmaxf(m, __shfl_xor(m, o, 64));
        float ev = __expf(v - m);
        float sm = ev;
#pragma unroll
        for (int o = 32; o; o >>= 1) sm += __shfl_xor(sm, o, 64);
        Al[r * ALS + lane] = f2b(ev * (1.f / sm));
    }
    __syncthreads();

    const ushort_t* xTb = xTF + (size_t)bh * XFRAG + lane * 8;
    bf16x8 af0 = *(const bf16x8*)&Al[ln * ALS + quad * 8];
    bf16x8 af1 = *(const bf16x8*)&Al[ln * ALS + quad * 8 + 32];

#pragma unroll 2
    for (int dt = wv; dt < 30; dt += 8) {
        bf16x8 b0 = *(const bf16x8*)(xTb + dt * 1024);
        bf16x8 b1 = *(const bf16x8*)(xTb + dt * 1024 + 512);
        f32x4 acc = (f32x4){0.f, 0.f, 0.f, 0.f};
        acc = MFMA16(af0, b0, acc, 0, 0, 0);
        acc = MFMA16(af1, b1, acc, 0, 0, 0);

        const int d = dt * 16 + ln;
        if (d < D) {
#pragma unroll
            for (int reg = 0; reg < 4; ++reg) {
                const int i = i0 + quad * 4 + reg;
                outf[((size_t)bh * 64 + i) * D + d] = acc[reg];
            }
        }
    }
}

// ---------------- launch ----------------
extern "C" void kernel_launch(void* const* d_in, const int* in_sizes, int n_in,
                              void* d_out, int out_size, void* d_ws, size_t ws_size,
                              hipStream_t stream) {
    const int*   q1       = (const int*)  d_in[0];
    const int*   q2       = (const int*)  d_in[1];
    const int*   q1_len   = (const int*)  d_in[2];
    const int*   q2_len   = (const int*)  d_in[3];
    const int*   q1c      = (const int*)  d_in[4];
    const int*   q2c      = (const int*)  d_in[5];
    const float* word_emb = (const float*)d_in[6];
    const float* char_emb = (const float*)d_in[7];
    const float* w3       = (const float*)d_in[8];
    const float* b3       = (const float*)d_in[9];
    const float* w4       = (const float*)d_in[10];
    const float* b4       = (const float*)d_in[11];
    const float* w5       = (const float*)d_in[12];
    const float* b5       = (const float*)d_in[13];
    const float* hw_w     = (const float*)d_in[14];
    const float* hw_b     = (const float*)d_in[15];
    const float* attn_w   = (const float*)d_in[16];
    const float* attn_b   = (const float*)d_in[17];
    float* out = (float*)d_out;

    float*    buf0    = (float*)d_ws;                          // 2*NT*D f32 (x2)
    float*    buf1    = buf0 + (size_t)2 * NT * D;             // (unused, layout keep)
    float*    bias160 = buf1 + (size_t)2 * NT * D;             // 160 f32
    ushort_t* xbFa    = (ushort_t*)(bias160 + 160);            // 2*NT*DP bf16 (fragment-major)
    ushort_t* xbFb    = xbFa + (size_t)2 * NT * DP;            // 2*NT*DP bf16
    ushort_t* Wb16F   = xbFb + (size_t)2 * NT * DP;            // WBF_N bf16
    ushort_t* WpadF   = Wb16F + (size_t)WBF_N;                 // WPF_N bf16
    ushort_t* ceb16   = WpadF + (size_t)WPF_N;                 // 100*64 bf16
    ushort_t* xw3Fa   = ceb16 + (size_t)100 * 64;              // NBH*XFRAG bf16
    ushort_t* xTFa    = xw3Fa + (size_t)NBH * XFRAG;           // NBH*XFRAG bf16
    ushort_t* xw3Fb   = xTFa  + (size_t)NBH * XFRAG;           // NBH*XFRAG bf16
    ushort_t* xTFb    = xw3Fb + (size_t)NBH * XFRAG;           // NBH*XFRAG bf16
    float*    s1a     = (float*)(xTFb + (size_t)NBH * XFRAG);  // 2*NT f32
    float*    s2a     = s1a + (size_t)2 * NT;
    float*    s1b     = s2a + (size_t)2 * NT;
    float*    s2b     = s1b + (size_t)2 * NT;

    // 1. weight prep
    prep_kernel<<<(WBF_N + WPF_N + 160 + 100 * 64 + 255) / 256, 256, 0, stream>>>(
        hw_w, w3, b3, w4, b4, w5, b5, char_emb, Wb16F, WpadF, bias160, ceb16);

    // 2. megafront: embed + conv + highway1 + highway2 + attn-prep0
    //    -> buf0 (x2 f32), xbFa, xw3Fa, xTFa, s1a/s2a
    megafront_kernel<<<512, 512, 0, stream>>>(
        q1, q2, q1c, q2c, word_emb, ceb16, WpadF, bias160, Wb16F, hw_b,
        attn_w, buf0, xbFa, xw3Fa, xTFa, s1a, s2a);

    // 3. attn core layer 0 + attn-prep layer 1
    attn_core_prep_kernel<<<512, 512, 0, stream>>>(
        buf0, xbFa, xw3Fa, xTFa, s1a, s2a, q1_len, q2_len, attn_b, attn_w,
        xbFb, xw3Fb, xTFb, s1b, s2b);

    // 4. attn core layer 1 -> out
    attn_core_final_kernel<<<512, 512, 0, stream>>>(
        xbFb, xw3Fb, xTFb, s1b, s2b, q1_len, q2_len, attn_b, out);
}